// Round 7
// baseline (2917.882 us; speedup 1.0000x reference)
//
#include <hip/hip_runtime.h>

// ---------- types / helpers ----------
typedef __attribute__((ext_vector_type(8))) short short8;   // 8 x bf16 bits
typedef __attribute__((ext_vector_type(4))) float float4v;
typedef __attribute__((ext_vector_type(4))) unsigned short u16x4;

__device__ __forceinline__ float bf2f(unsigned short u) {
    union { unsigned int i; float f; } v; v.i = ((unsigned int)u) << 16; return v.f;
}
__device__ __forceinline__ unsigned short f2bf(float f) {   // round-to-nearest-even
    union { float f; unsigned int u; } v; v.f = f;
    unsigned int u = v.u;
    return (unsigned short)((u + 0x7fffu + ((u >> 16) & 1u)) >> 16);
}
__device__ __forceinline__ void load_lds16(const void* g, void* l) {
    __builtin_amdgcn_global_load_lds((const __attribute__((address_space(1))) void*)g,
                                     (__attribute__((address_space(3))) void*)l, 16, 0, 0);
}
__device__ __forceinline__ float wred(float v) {
#pragma unroll
    for (int o = 32; o > 0; o >>= 1) v += __shfl_down(v, o);
    return __shfl(v, 0);
}

// ---------- problem dims ----------
#define BB 8192
#define DD 1024
#define HH 2048
#define HM 1024
#define CC 1000
#define CP 1024
#define EE 8
#define CAP2 18432          // 72 row tiles of 256 (expert capacity, 256-padded)
#define NT2 72

// ---------- ws layout (bytes) ----------
#define OFF_XHI   0ull
#define OFF_XLO   16777216ull
#define OFF_W1TH  33554432ull
#define OFF_W1TL  37748736ull
#define OFF_W2T   41943040ull
#define OFF_HPH   50331648ull   // ends 83886080
#define OFF_HPL   83886080ull   // ends 117440512
#define OFF_M2    117440512ull  // m2th (0.5MB) + m2tl (0.5MB)
#define OFF_B2    118489088ull
#define OFF_FEATS 118490112ull  // bf16 feats, ends 152044544 (LIVE through expert L1)
#define OFF_PK    152044544ull  // ends 156238848 (kwt hi/lo early, pkbuf mid, slots late)
#define OFF_H1    0ull          // alias: x/w1t/w2t/hph region — dead after pk split3; 75.5MB
#define OFF_EW1T  156238848ull  // ends 223347712
#define OFF_H2    156238848ull  // alias ew1T (dead after expert L1); 37.7MB
#define OFF_EW2T  223347712ull
#define OFF_EW3T  256902144ull
#define OFF_TOPE  273818624ull
#define OFF_TOPW  273884160ull
#define OFF_CNT   273949696ull
// aliases
#define OFF_FW2H  OFF_HPH                  // 8.4MB, dead before l1 writes hph
#define OFF_FW2L  (OFF_HPH + 8388608ull)
#define OFF_KWTH  OFF_PK                   // 0.5MB, dead before pkred writes pkbuf
#define OFF_KWTL  (OFF_PK + 524288ull)
#define OFF_M2P   OFF_FEATS                // 8MB partials, dead before l2 writes feats
#define OFF_PKP   0ull                     // 16.8MB partials, dead before h1 written
#define OFF_WSL   OFF_PK                   // wslot[18432] f32 — pkbuf dead after k_route
#define OFF_RSL   (OFF_PK + 73728ull)      // rowslot[18432] i32
#define OFF_SL    (OFF_PK + 147456ull)     // sl[16384] i32: b -> its two slots
#define OFF_PF    0ull                     // pf[CAP2][CP] f32 (75.5MB) — aliases h1 (dead after expert L2)

// ---------- XCD-chunked grid swizzle ----------
#define SWZ_G 4
__device__ __forceinline__ void remap_xy(int& x, int& y) {
    const int nbx = gridDim.x, nby = gridDim.y;
    int lin = blockIdx.y * nbx + blockIdx.x;
    int xcd = lin & 7, idx = lin >> 3;
    int rpx = nbx >> 3;                 // row-tiles per xcd
    int gs  = rpx * SWZ_G;              // blocks per col-group within chunk
    int grp = idx / gs, wi = idx - grp * gs;
    int xl  = wi / SWZ_G, yl = wi - xl * SWZ_G;
    x = xcd * rpx + xl;
    y = grp * SWZ_G + yl;
}

// ---------- conversion kernels ----------
__global__ __launch_bounds__(256) void k_split_convert(const float* __restrict__ in,
    unsigned short* __restrict__ hi, unsigned short* __restrict__ lo, int n)
{
    int i = (blockIdx.x * 256 + threadIdx.x) * 4;
    if (i >= n) return;
    float4 v = *(const float4*)(in + i);
    unsigned short h0 = f2bf(v.x), h1 = f2bf(v.y), h2 = f2bf(v.z), h3 = f2bf(v.w);
    u16x4 hv = {h0, h1, h2, h3};
    u16x4 lv = {f2bf(v.x - bf2f(h0)), f2bf(v.y - bf2f(h1)),
                f2bf(v.z - bf2f(h2)), f2bf(v.w - bf2f(h3))};
    *(u16x4*)(hi + i) = hv;
    *(u16x4*)(lo + i) = lv;
}

// out[b][n][k] = in[b][k][n]  (bf16, zero-pad n >= N up to Npad)
template<bool SPLIT>
__global__ __launch_bounds__(256) void k_transpose(const float* __restrict__ in,
    unsigned short* __restrict__ hi, unsigned short* __restrict__ lo, int K, int N, int Npad)
{
    __shared__ float tile[32][33];
    const float* src = in + (size_t)blockIdx.z * K * N;
    int n0 = blockIdx.x * 32, k0 = blockIdx.y * 32;
    int tx = threadIdx.x & 31, ty = threadIdx.x >> 5;
#pragma unroll
    for (int r = ty; r < 32; r += 8) {
        int n = n0 + tx;
        tile[r][tx] = (n < N) ? src[(size_t)(k0 + r) * N + n] : 0.f;
    }
    __syncthreads();
    size_t ob = (size_t)blockIdx.z * Npad * K;
    {
        int n  = threadIdx.x >> 3;          // 0..31  (output row within tile)
        int kq = (threadIdx.x & 7) * 4;     // 0..28  (output col quad, contiguous in K)
        u16x4 hv, lv;
#pragma unroll
        for (int i = 0; i < 4; ++i) {
            float v = tile[kq + i][n];
            unsigned short h = f2bf(v);
            hv[i] = h;
            lv[i] = SPLIT ? f2bf(v - bf2f(h)) : (unsigned short)0;
        }
        size_t o = ob + (size_t)(n0 + n) * K + k0 + kq;
        *(u16x4*)(hi + o) = hv;
        if (SPLIT) *(u16x4*)(lo + o) = lv;
    }
}

// ============================================================================
// BK=64 4-phase core (kept for k_l2 only: grid=256 is perfectly packed at 1/CU)
// ============================================================================
template<int NB>
__device__ __forceinline__ void gemm256(
    const unsigned short* __restrict__ a0, const unsigned short* __restrict__ a1,
    const unsigned short* __restrict__ b0, const unsigned short* __restrict__ b1,
    int K, unsigned short* L, float4v (&acc)[8][NB])
{
    const int tid = threadIdx.x;
    const int lane = tid & 63, w = tid >> 6;
    const int lrow = lane & 15, quad = (lane >> 4) & 3;
    const int wm = w >> 2, wn = w & 3;
    const int NT = K >> 6;
    constexpr int BSH  = NB * 2048;         // B half-tile shorts
    constexpr int BUFS = 16384 + 2 * BSH;   // per-buffer shorts
    constexpr int VM   = (NB == 4) ? 6 : 4; // steady-state vmcnt

    int aoff[8], boff[NB];
#pragma unroll
    for (int i = 0; i < 8; ++i) {
        int r = wm * 128 + i * 16 + lrow;
        aoff[i] = r * 32 + (quad ^ ((r >> 1) & 3)) * 8;
    }
#pragma unroll
    for (int j = 0; j < NB; ++j) {
        int r = wn * (NB * 16) + j * 16 + lrow;
        boff[j] = r * 32 + (quad ^ ((r >> 1) & 3)) * 8;
    }
    unsigned short* const dA = L + w * 512;
    unsigned short* const dB = L + 16384 + w * 512;

    auto stgA = [&](int t, int kh, int buf) {
        unsigned short* d = dA + buf * BUFS + kh * 8192;
        const int ko = t * 64 + kh * 32;
        load_lds16(a0 + ko, d);
        load_lds16(a1 + ko, d + 4096);
    };
    auto stgB = [&](int t, int kh, int buf) {
        unsigned short* d = dB + buf * BUFS + kh * BSH;
        const int ko = t * 64 + kh * 32;
        load_lds16(b0 + ko, d);
        if constexpr (NB == 4) load_lds16(b1 + ko, d + 4096);
    };

    stgA(0, 0, 0); stgA(0, 1, 0); stgB(0, 0, 0); stgB(0, 1, 0);
    if (NT > 1) { stgB(1, 0, 1); stgA(1, 0, 1); stgB(1, 1, 1); }
    asm volatile("s_waitcnt vmcnt(%0)" :: "i"(VM) : "memory");
    __builtin_amdgcn_s_barrier();

    short8 af[4], bfr[NB];
    for (int t = 0; t < NT; ++t) {
        const int buf = t & 1;
        const unsigned short* Lb = L + buf * BUFS;
        // ---- P1: M-lo, k0 ----
#pragma unroll
        for (int i = 0; i < 4; ++i) af[i]  = *(const short8*)(Lb + aoff[i]);
#pragma unroll
        for (int j = 0; j < NB; ++j) bfr[j] = *(const short8*)(Lb + 16384 + boff[j]);
        if (t + 1 < NT) stgA(t + 1, 1, buf ^ 1);
        __builtin_amdgcn_s_barrier();
        __builtin_amdgcn_s_setprio(1);
#pragma unroll
        for (int i = 0; i < 4; ++i)
#pragma unroll
            for (int j = 0; j < NB; ++j)
                acc[i][j] = __builtin_amdgcn_mfma_f32_16x16x32_bf16(af[i], bfr[j], acc[i][j], 0, 0, 0);
        __builtin_amdgcn_s_setprio(0);
        __builtin_amdgcn_s_barrier();
        // ---- P2: M-hi, k0 ----
#pragma unroll
        for (int i = 0; i < 4; ++i) af[i] = *(const short8*)(Lb + aoff[4 + i]);
        if (t + 2 < NT) stgB(t + 2, 0, buf);
        __builtin_amdgcn_s_barrier();
        __builtin_amdgcn_s_setprio(1);
#pragma unroll
        for (int i = 0; i < 4; ++i)
#pragma unroll
            for (int j = 0; j < NB; ++j)
                acc[4 + i][j] = __builtin_amdgcn_mfma_f32_16x16x32_bf16(af[i], bfr[j], acc[4 + i][j], 0, 0, 0);
        __builtin_amdgcn_s_setprio(0);
        __builtin_amdgcn_s_barrier();
        // ---- P3: M-lo, k1 ----
#pragma unroll
        for (int i = 0; i < 4; ++i) af[i]  = *(const short8*)(Lb + 8192 + aoff[i]);
#pragma unroll
        for (int j = 0; j < NB; ++j) bfr[j] = *(const short8*)(Lb + 16384 + BSH + boff[j]);
        if (t + 2 < NT) stgA(t + 2, 0, buf);
        __builtin_amdgcn_s_barrier();
        __builtin_amdgcn_s_setprio(1);
#pragma unroll
        for (int i = 0; i < 4; ++i)
#pragma unroll
            for (int j = 0; j < NB; ++j)
                acc[i][j] = __builtin_amdgcn_mfma_f32_16x16x32_bf16(af[i], bfr[j], acc[i][j], 0, 0, 0);
        __builtin_amdgcn_s_setprio(0);
        __builtin_amdgcn_s_barrier();
        // ---- P4: M-hi, k1 ----
#pragma unroll
        for (int i = 0; i < 4; ++i) af[i] = *(const short8*)(Lb + 8192 + aoff[4 + i]);
        if (t + 2 < NT) {
            stgB(t + 2, 1, buf);
            asm volatile("s_waitcnt vmcnt(%0)" :: "i"(VM) : "memory");
        } else {
            asm volatile("s_waitcnt vmcnt(0)" ::: "memory");
        }
        __builtin_amdgcn_s_barrier();
        __builtin_amdgcn_s_setprio(1);
#pragma unroll
        for (int i = 0; i < 4; ++i)
#pragma unroll
            for (int j = 0; j < NB; ++j)
                acc[4 + i][j] = __builtin_amdgcn_mfma_f32_16x16x32_bf16(af[i], bfr[j], acc[4 + i][j], 0, 0, 0);
        __builtin_amdgcn_s_setprio(0);
        __builtin_amdgcn_s_barrier();
    }
}

// ============================================================================
// BK=32 2-phase core, half LDS -> 2 blocks/CU. 512 thr = 8 waves (2M x 4N).
// LDS/buf: A 256x32 (8192 sh) + B NB*64 x 32 (NB*2048 sh); x2 buf = 64KB (NB=4)
// / 48KB (NB=2). Per tile: stage ALL of tile t+1 -> buf^1 (top), P1 Mlo, P2 Mhi,
// vmcnt(0), ONE barrier. 32 MFMA/barrier at NB=4.
// R7 hardening: raw s_barrier is NOT a compiler memory fence (cf. rule #18 —
// hipcc can hoist ops across inline-asm waits). sched_barrier(0) is placed
// immediately after every s_barrier so next-tile ds_reads / global_load_lds
// cannot hoist above the barrier (WAR/RAW vs other waves), and after the
// vmcnt(0) so nothing sinks between drain and barrier. Zero runtime cost.
// ============================================================================
template<int NB>
__device__ __forceinline__ void gemm256b(
    const unsigned short* __restrict__ a0, const unsigned short* __restrict__ a1,
    const unsigned short* __restrict__ b0, const unsigned short* __restrict__ b1,
    int K, unsigned short* L, float4v (&acc)[8][NB])
{
    const int tid = threadIdx.x;
    const int lane = tid & 63, w = tid >> 6;
    const int lrow = lane & 15, quad = (lane >> 4) & 3;
    const int wm = w >> 2, wn = w & 3;
    const int NT = K >> 5;
    constexpr int BUFS = 8192 + NB * 2048;  // per-buffer shorts

    int aoff[8], boff[NB];
#pragma unroll
    for (int i = 0; i < 8; ++i) {
        int r = wm * 128 + i * 16 + lrow;
        aoff[i] = r * 32 + (quad ^ ((r >> 1) & 3)) * 8;
    }
#pragma unroll
    for (int j = 0; j < NB; ++j) {
        int r = wn * (NB * 16) + j * 16 + lrow;
        boff[j] = r * 32 + (quad ^ ((r >> 1) & 3)) * 8;
    }
    unsigned short* const dA = L + w * 512;
    unsigned short* const dB = L + 8192 + w * 512;

    auto stg = [&](int t, int buf) {            // stage full K-tile t (A + B)
        unsigned short* da = dA + buf * BUFS;
        unsigned short* db = dB + buf * BUFS;
        const int ko = t * 32;
        load_lds16(a0 + ko, da);                // M-lo rows
        load_lds16(a1 + ko, da + 4096);         // M-hi rows
        load_lds16(b0 + ko, db);
        if constexpr (NB == 4) load_lds16(b1 + ko, db + 4096);
    };

    // prologue: tile 0
    stg(0, 0);
    asm volatile("s_waitcnt vmcnt(0)" ::: "memory");
    __builtin_amdgcn_sched_barrier(0);
    __builtin_amdgcn_s_barrier();
    __builtin_amdgcn_sched_barrier(0);

    short8 af[4], bfr[NB];
    for (int t = 0; t < NT; ++t) {
        const int buf = t & 1;
        const unsigned short* Lb = L + buf * BUFS;
        if (t + 1 < NT) stg(t + 1, buf ^ 1);    // issue early: full tile to land
        // ---- P1: M-lo ----
#pragma unroll
        for (int i = 0; i < 4; ++i) af[i]  = *(const short8*)(Lb + aoff[i]);
#pragma unroll
        for (int j = 0; j < NB; ++j) bfr[j] = *(const short8*)(Lb + 8192 + boff[j]);
        __builtin_amdgcn_s_setprio(1);
#pragma unroll
        for (int i = 0; i < 4; ++i)
#pragma unroll
            for (int j = 0; j < NB; ++j)
                acc[i][j] = __builtin_amdgcn_mfma_f32_16x16x32_bf16(af[i], bfr[j], acc[i][j], 0, 0, 0);
        __builtin_amdgcn_s_setprio(0);
        // ---- P2: M-hi (reuse bfr) ----
#pragma unroll
        for (int i = 0; i < 4; ++i) af[i] = *(const short8*)(Lb + aoff[4 + i]);
        __builtin_amdgcn_s_setprio(1);
#pragma unroll
        for (int i = 0; i < 4; ++i)
#pragma unroll
            for (int j = 0; j < NB; ++j)
                acc[4 + i][j] = __builtin_amdgcn_mfma_f32_16x16x32_bf16(af[i], bfr[j], acc[4 + i][j], 0, 0, 0);
        __builtin_amdgcn_s_setprio(0);
        asm volatile("s_waitcnt vmcnt(0)" ::: "memory");
        __builtin_amdgcn_sched_barrier(0);
        __builtin_amdgcn_s_barrier();
        __builtin_amdgcn_sched_barrier(0);
    }
}

// ---------- layer 1: split (bf16x2) GEMM, relu, split-store (128^2 structure) ----------
__global__ __launch_bounds__(256, 2) void k_l1(
    const unsigned short* __restrict__ xh, const unsigned short* __restrict__ xl,
    const unsigned short* __restrict__ wh, const unsigned short* __restrict__ wl,
    const float* __restrict__ bias, unsigned short* __restrict__ oh, unsigned short* __restrict__ ol)
{
    __shared__ __align__(16) unsigned short Ash[4096], Asl[4096], Bsh[4096], Bsl[4096];
    const int K = DD, N = HH;
    int bx, by; remap_xy(bx, by);
    const int row0 = bx * 128, col0 = by * 128;
    const int t = threadIdx.x, lane = t & 63, w = t >> 6;
    const int lrow = lane & 15, quad = lane >> 4;
    const int swz = (quad ^ ((lrow >> 1) & 3)) * 8;
    const int wr = (w & 1) * 64, wc = (w >> 1) * 64;
    float4v acc[4][4] = {};
    for (int k0 = 0; k0 < K; k0 += 32) {
#pragma unroll
        for (int p = 0; p < 2; ++p) {
            int c = p * 256 + t;
            int r = c >> 2, q = (c & 3) ^ ((r >> 1) & 3);
            size_t ga = (size_t)(row0 + r) * K + k0 + q * 8;
            size_t gb = (size_t)(col0 + r) * K + k0 + q * 8;
            int lo_ = (p * 256 + w * 64) * 8;
            load_lds16(xh + ga, Ash + lo_);
            load_lds16(xl + ga, Asl + lo_);
            load_lds16(wh + gb, Bsh + lo_);
            load_lds16(wl + gb, Bsl + lo_);
        }
        __syncthreads();
        short8 ah[4], al[4], bh[4], bl[4];
#pragma unroll
        for (int i = 0; i < 4; ++i) {
            int o = (wr + i * 16 + lrow) * 32 + swz;
            ah[i] = *(const short8*)(Ash + o);
            al[i] = *(const short8*)(Asl + o);
        }
#pragma unroll
        for (int j = 0; j < 4; ++j) {
            int o = (wc + j * 16 + lrow) * 32 + swz;
            bh[j] = *(const short8*)(Bsh + o);
            bl[j] = *(const short8*)(Bsl + o);
        }
#pragma unroll
        for (int i = 0; i < 4; ++i)
#pragma unroll
            for (int j = 0; j < 4; ++j) {
                float4v a0 = __builtin_amdgcn_mfma_f32_16x16x32_bf16(al[i], bh[j], acc[i][j], 0, 0, 0);
                a0 = __builtin_amdgcn_mfma_f32_16x16x32_bf16(ah[i], bl[j], a0, 0, 0, 0);
                acc[i][j] = __builtin_amdgcn_mfma_f32_16x16x32_bf16(ah[i], bh[j], a0, 0, 0, 0);
            }
        __syncthreads();
    }
#pragma unroll
    for (int i = 0; i < 4; ++i)
#pragma unroll
        for (int r = 0; r < 4; ++r) {
            int row = row0 + wr + i * 16 + quad * 4 + r;
            size_t base = (size_t)row * N;
#pragma unroll
            for (int j = 0; j < 4; ++j) {
                int col = col0 + wc + j * 16 + lrow;
                float v = fmaxf(acc[i][j][r] + bias[col], 0.f);
                unsigned short h = f2bf(v);
                oh[base + col] = h;
                ol[base + col] = f2bf(v - bf2f(h));
            }
        }
}

// ---------- generic 3-term split GEMM, N=128, split-K, fp32 partial out ----------
__global__ __launch_bounds__(256, 2) void k_split3(
    const unsigned short* __restrict__ ah_, const unsigned short* __restrict__ al_,
    const unsigned short* __restrict__ bh_, const unsigned short* __restrict__ bl_,
    float* __restrict__ out, int K, int klen)
{
    __shared__ __align__(16) unsigned short Ash[4096], Asl[4096], Bsh[4096], Bsl[4096];
    const int row0 = blockIdx.x * 128;
    const int kb = blockIdx.y * klen;
    out += (size_t)blockIdx.y * gridDim.x * 128 * 128;
    const int t = threadIdx.x, lane = t & 63, w = t >> 6;
    const int lrow = lane & 15, quad = lane >> 4;
    const int swz = (quad ^ ((lrow >> 1) & 3)) * 8;
    const int wr = (w & 1) * 64, wc = (w >> 1) * 64;
    float4v acc[4][4] = {};
    for (int k0 = kb; k0 < kb + klen; k0 += 32) {
#pragma unroll
        for (int p = 0; p < 2; ++p) {
            int c = p * 256 + t;
            int r = c >> 2, q = (c & 3) ^ ((r >> 1) & 3);
            size_t ga = (size_t)(row0 + r) * K + k0 + q * 8;
            size_t gb = (size_t)r * K + k0 + q * 8;           // B has exactly 128 rows
            int lo_ = (p * 256 + w * 64) * 8;
            load_lds16(ah_ + ga, Ash + lo_);
            load_lds16(al_ + ga, Asl + lo_);
            load_lds16(bh_ + gb, Bsh + lo_);
            load_lds16(bl_ + gb, Bsl + lo_);
        }
        __syncthreads();
        short8 ah[4], al[4], bh[4], bl[4];
#pragma unroll
        for (int i = 0; i < 4; ++i) {
            int o = (wr + i * 16 + lrow) * 32 + swz;
            ah[i] = *(const short8*)(Ash + o);
            al[i] = *(const short8*)(Asl + o);
        }
#pragma unroll
        for (int j = 0; j < 4; ++j) {
            int o = (wc + j * 16 + lrow) * 32 + swz;
            bh[j] = *(const short8*)(Bsh + o);
            bl[j] = *(const short8*)(Bsl + o);
        }
#pragma unroll
        for (int i = 0; i < 4; ++i)
#pragma unroll
            for (int j = 0; j < 4; ++j) {
                float4v a0 = __builtin_amdgcn_mfma_f32_16x16x32_bf16(al[i], bh[j], acc[i][j], 0, 0, 0);
                a0 = __builtin_amdgcn_mfma_f32_16x16x32_bf16(ah[i], bl[j], a0, 0, 0, 0);
                acc[i][j] = __builtin_amdgcn_mfma_f32_16x16x32_bf16(ah[i], bh[j], a0, 0, 0, 0);
            }
        __syncthreads();
    }
#pragma unroll
    for (int i = 0; i < 4; ++i)
#pragma unroll
        for (int r = 0; r < 4; ++r) {
            int row = row0 + wr + i * 16 + quad * 4 + r;
            size_t base = (size_t)row * 128;
#pragma unroll
            for (int j = 0; j < 4; ++j) {
                int col = wc + j * 16 + lrow;
                out[base + col] = acc[i][j][r];
            }
        }
}

// ---------- M2 reduce: sum 8 partials, transpose, split to bf16 hi/lo ----------
__global__ __launch_bounds__(256) void k_m2red(const float* __restrict__ p,
    unsigned short* __restrict__ th, unsigned short* __restrict__ tl)
{
    __shared__ float tile[32][33];
    const int h0 = blockIdx.x * 32, c0 = blockIdx.y * 32;
    const int t = threadIdx.x;
    {
        int r = t >> 3, cq = (t & 7) * 4;
        size_t base = (size_t)(h0 + r) * 128 + c0 + cq;
        float4 s = *(const float4*)(p + base);
#pragma unroll
        for (int ks = 1; ks < 8; ++ks) {
            float4 v = *(const float4*)(p + (size_t)ks * HH * 128 + base);
            s.x += v.x; s.y += v.y; s.z += v.z; s.w += v.w;
        }
        tile[r][cq] = s.x; tile[r][cq + 1] = s.y; tile[r][cq + 2] = s.z; tile[r][cq + 3] = s.w;
    }
    __syncthreads();
    {
        int cr = t >> 3, hq = (t & 7) * 4;
        u16x4 hv, lv;
#pragma unroll
        for (int i = 0; i < 4; ++i) {
            float v = tile[hq + i][cr];
            unsigned short h = f2bf(v);
            hv[i] = h; lv[i] = f2bf(v - bf2f(h));
        }
        size_t o = (size_t)(c0 + cr) * HH + h0 + hq;
        *(u16x4*)(th + o) = hv;
        *(u16x4*)(tl + o) = lv;
    }
}

// ---------- pk reduce: sum 4 partials + bias ----------
__global__ __launch_bounds__(256) void k_pkred(const float* __restrict__ p,
    const float* __restrict__ b2, float* __restrict__ out)
{
    int idx = blockIdx.x * 256 + threadIdx.x;
    const size_t S = (size_t)BB * 128;
    out[idx] = p[idx] + p[idx + S] + p[idx + 2 * S] + p[idx + 3 * S] + b2[idx & 127];
}

// ---------- layer 2: single bf16 GEMM -> feats bf16 (no relu), 256^2 BK=64 ----------
__global__ __launch_bounds__(512, 2) void k_l2(const unsigned short* __restrict__ A,
    const unsigned short* __restrict__ Bt, const float* __restrict__ bias,
    unsigned short* __restrict__ outb)
{
    __shared__ __align__(16) unsigned short L[65536];
    const int K = HH, N = HH;
    int bx, by; remap_xy(bx, by);
    const int row0 = bx * 256, col0 = by * 256;
    const int tid = threadIdx.x;
    const int r0 = tid >> 2, c0 = tid & 3;
    const int csw = (c0 ^ ((r0 >> 1) & 3)) * 8;
    const unsigned short* a0 = A + (size_t)(row0 + r0) * K + csw;
    const unsigned short* a1 = a0 + (size_t)128 * K;
    const unsigned short* b0 = Bt + (size_t)(col0 + r0) * K + csw;
    const unsigned short* b1 = b0 + (size_t)128 * K;
    float4v acc[8][4] = {};
    gemm256<4>(a0, a1, b0, b1, K, L, acc);
    const int lane = tid & 63, w = tid >> 6;
    const int lrow = lane & 15, quad = (lane >> 4) & 3;
    const int wm = w >> 2, wn = w & 3;
#pragma unroll
    for (int ii = 0; ii < 8; ++ii)
#pragma unroll
        for (int rr = 0; rr < 4; ++rr) {
            int row = row0 + wm * 128 + ii * 16 + quad * 4 + rr;
            size_t base = (size_t)row * N;
#pragma unroll
            for (int j = 0; j < 4; ++j) {
                int col = col0 + wn * 64 + j * 16 + lrow;
                outb[base + col] = f2bf(acc[ii][j][rr] + bias[col]);
            }
        }
}

// ---------- expert GEMM (relu, bf16 out), 256xBN BK=32 2/CU; IND: rows via rowslot ----------
template<bool IND, int NB>
__global__ __launch_bounds__(512, 4) void k_le(const unsigned short* __restrict__ A,
    const unsigned short* __restrict__ WT, const float* __restrict__ bias,
    unsigned short* __restrict__ out, const int* __restrict__ offs,
    const int* __restrict__ rowslot, int N, int K)
{
    __shared__ __align__(16) unsigned short L[2 * (8192 + NB * 2048)];
    int bx, by; remap_xy(bx, by);
    const int row0 = bx * 256;
    if (row0 >= offs[8]) return;
    int e = 0;
#pragma unroll
    for (int i = 1; i < 8; ++i) if (offs[i] <= row0) e = i;
    const unsigned short* Bt = WT + (size_t)e * N * K;
    const float* bs = bias + (size_t)e * N;
    const int col0 = by * (NB * 64);
    const int tid = threadIdx.x;
    const int r0 = tid >> 2, c0 = tid & 3;
    const int csw = (c0 ^ ((r0 >> 1) & 3)) * 8;
    const int gr0 = IND ? rowslot[row0 + r0] : (row0 + r0);
    const int gr1 = IND ? rowslot[row0 + 128 + r0] : (row0 + 128 + r0);
    const unsigned short* a0 = A + (size_t)gr0 * K + csw;
    const unsigned short* a1 = A + (size_t)gr1 * K + csw;
    const unsigned short* b0 = Bt + (size_t)(col0 + r0) * K + csw;
    const unsigned short* b1 = b0 + (size_t)128 * K;
    float4v acc[8][NB] = {};
    gemm256b<NB>(a0, a1, b0, b1, K, L, acc);
    const int lane = tid & 63, w = tid >> 6;
    const int lrow = lane & 15, quad = (lane >> 4) & 3;
    const int wm = w >> 2, wn = w & 3;
#pragma unroll
    for (int ii = 0; ii < 8; ++ii)
#pragma unroll
        for (int rr = 0; rr < 4; ++rr) {
            int row = row0 + wm * 128 + ii * 16 + quad * 4 + rr;
            size_t base = (size_t)row * N;
#pragma unroll
            for (int j = 0; j < NB; ++j) {
                int col = col0 + wn * (NB * 16) + j * 16 + lrow;
                out[base + col] = f2bf(fmaxf(acc[ii][j][rr] + bs[col], 0.f));
            }
        }
}

// ---------- final expert GEMM: weighted per-slot partial (NO atomics), BK=32 ----------
__global__ __launch_bounds__(512, 4) void k_final(const unsigned short* __restrict__ A,
    const unsigned short* __restrict__ WT, const float* __restrict__ bias,
    float* __restrict__ pf, const int* __restrict__ offs,
    const float* __restrict__ wslot)
{
    constexpr int NB = 2;
    __shared__ __align__(16) unsigned short L[2 * (8192 + NB * 2048)];
    const int N = CP, K = HM;
    int bx, by; remap_xy(bx, by);
    const int row0 = bx * 256;
    if (row0 >= offs[8]) return;
    int e = 0;
#pragma unroll
    for (int i = 1; i < 8; ++i) if (offs[i] <= row0) e = i;
    const unsigned short* Bt = WT + (size_t)e * N * K;
    const float* bs = bias + (size_t)e * CC;
    const int col0 = by * (NB * 64);
    const int tid = threadIdx.x;
    const int r0 = tid >> 2, c0 = tid & 3;
    const int csw = (c0 ^ ((r0 >> 1) & 3)) * 8;
    const unsigned short* a0 = A + (size_t)(row0 + r0) * K + csw;
    const unsigned short* a1 = a0 + (size_t)128 * K;
    const unsigned short* b0 = Bt + (size_t)(col0 + r0) * K + csw;
    float4v acc[8][NB] = {};
    gemm256b<NB>(a0, a1, b0, b0, K, L, acc);
    const int lane = tid & 63, w = tid >> 6;
    const int lrow = lane & 15, quad = (lane >> 4) & 3;
    const int wm = w >> 2, wn = w & 3;
#pragma unroll
    for (int ii = 0; ii < 8; ++ii)
#pragma unroll
        for (int rr = 0; rr < 4; ++rr) {
            int row = row0 + wm * 128 + ii * 16 + quad * 4 + rr;
            float wv = wslot[row];
            if (wv != 0.f) {
                float* prow = pf + (size_t)row * CP;
#pragma unroll
                for (int j = 0; j < NB; ++j) {
                    int col = col0 + wn * (NB * 16) + j * 16 + lrow;
                    if (col < CC) prow[col] = wv * (acc[ii][j][rr] + bs[col]);
                }
            }
        }
}

// ---------- combine: outF[b][c] = pf[sl[2b]][c] + pf[sl[2b+1]][c] ----------
__global__ __launch_bounds__(256) void k_combine(const float* __restrict__ pf,
    const int* __restrict__ sl, float* __restrict__ outF)
{
    int b = blockIdx.x;
    int c = threadIdx.x * 4;
    if (c >= CC) return;
    int s0 = sl[b * 2], s1 = sl[b * 2 + 1];
    float4 v0 = *(const float4*)(pf + (size_t)s0 * CP + c);
    float4 v1 = *(const float4*)(pf + (size_t)s1 * CP + c);
    float4 r; r.x = v0.x + v1.x; r.y = v0.y + v1.y; r.z = v0.z + v1.z; r.w = v0.w + v1.w;
    *(float4*)(outF + (size_t)b * CC + c) = r;
}

// ---------- b2[c] = sum_j fb2[j]*kw[j,c] + kb[c] ----------
__global__ __launch_bounds__(64) void k_bias2(const float* __restrict__ fb2,
    const float* __restrict__ kw, const float* __restrict__ kb, float* __restrict__ b2)
{
    int c = blockIdx.x, lane = threadIdx.x;
    float s = 0.f;
    for (int j = lane; j < HH; j += 64) s += fb2[j] * kw[(size_t)j * 128 + c];
    s = wred(s);
    if (lane == 0) b2[c] = s + kb[c];
}

// ---------- routing ----------
__global__ __launch_bounds__(64) void k_route(const float* __restrict__ pk,
    const float* __restrict__ keys, float* __restrict__ wout, float* __restrict__ tout,
    float* __restrict__ simout, int* __restrict__ top_e, float* __restrict__ top_w,
    int* __restrict__ cnt)
{
    int b = blockIdx.x, lane = threadIdx.x;
    float2 v = *(const float2*)&pk[(size_t)b * 128 + lane * 2];
    float inv = 1.f / fmaxf(sqrtf(wred(v.x * v.x + v.y * v.y)), 1e-12f);
    float sims[8];
#pragma unroll
    for (int e = 0; e < 8; ++e) {
        float2 kv = *(const float2*)&keys[e * 128 + lane * 2];
        float kinv = 1.f / fmaxf(sqrtf(wred(kv.x * kv.x + kv.y * kv.y)), 1e-12f);
        float d = wred(v.x * kv.x + v.y * kv.y);
        sims[e] = d * inv * kinv;
    }
    if (lane == 0) {
        int i1 = 0; float v1 = sims[0];
#pragma unroll
        for (int e = 1; e < 8; ++e) if (sims[e] > v1) { v1 = sims[e]; i1 = e; }
        int i2 = -1; float v2 = -1e30f;
#pragma unroll
        for (int e = 0; e < 8; ++e) if (e != i1 && sims[e] > v2) { v2 = sims[e]; i2 = e; }
        float e2 = expf(v2 - v1);
        float w1 = 1.f / (1.f + e2), w2 = e2 / (1.f + e2);
#pragma unroll
        for (int e = 0; e < 8; ++e) simout[(size_t)b * 8 + e] = sims[e];
        wout[(size_t)b * 8 + i1] = w1;
        wout[(size_t)b * 8 + i2] = w2;
        tout[(size_t)b * 2] = (float)i1; tout[(size_t)b * 2 + 1] = (float)i2;
        top_e[b * 2] = i1; top_e[b * 2 + 1] = i2;
        top_w[b * 2] = w1; top_w[b * 2 + 1] = w2;
        atomicAdd(&cnt[i1], 1); atomicAdd(&cnt[i2], 1);
    }
}

__global__ void k_offs(const int* __restrict__ cnt, int* __restrict__ offs)
{
    if (threadIdx.x == 0) {
        int o = 0;
        for (int e = 0; e < 8; ++e) { offs[e] = o; o += ((cnt[e] + 255) >> 8) << 8; }
        offs[8] = o;
    }
}

__global__ __launch_bounds__(256) void k_scatter(const int* __restrict__ top_e,
    const float* __restrict__ top_w, const int* __restrict__ offs, int* __restrict__ cnt2,
    int* __restrict__ rowslot, float* __restrict__ wslot, int* __restrict__ sl)
{
    int b = blockIdx.x * 256 + threadIdx.x;
    if (b >= BB) return;
#pragma unroll
    for (int j = 0; j < 2; ++j) {
        int e = top_e[b * 2 + j];
        int idx = atomicAdd(&cnt2[e], 1);
        int s = offs[e] + idx;
        rowslot[s] = b;
        wslot[s] = top_w[b * 2 + j];
        sl[b * 2 + j] = s;
    }
}

// ---------- launch ----------
extern "C" void kernel_launch(void* const* d_in, const int* in_sizes, int n_in,
                              void* d_out, int out_size, void* d_ws, size_t ws_size,
                              hipStream_t stream)
{
    const float* x    = (const float*)d_in[0];
    const float* fw1  = (const float*)d_in[1];
    const float* fb1  = (const float*)d_in[2];
    const float* fw2  = (const float*)d_in[3];
    const float* fb2  = (const float*)d_in[4];
    const float* kw   = (const float*)d_in[5];
    const float* kb   = (const float*)d_in[6];
    const float* keys = (const float*)d_in[7];
    const float* ew1  = (const float*)d_in[8];
    const float* eb1  = (const float*)d_in[9];
    const float* ew2  = (const float*)d_in[10];
    const float* eb2  = (const float*)d_in[11];
    const float* ew3  = (const float*)d_in[12];
    const float* eb3  = (const float*)d_in[13];

    char* W = (char*)d_ws;
    unsigned short* x_hi  = (unsigned short*)(W + OFF_XHI);
    unsigned short* x_lo  = (unsigned short*)(W + OFF_XLO);
    unsigned short* w1th  = (unsigned short*)(W + OFF_W1TH);
    unsigned short* w1tl  = (unsigned short*)(W + OFF_W1TL);
    unsigned short* w2t   = (unsigned short*)(W + OFF_W2T);
    unsigned short* hph   = (unsigned short*)(W + OFF_HPH);
    unsigned short* hpl   = (unsigned short*)(W + OFF_HPL);
    unsigned short* fw2h  = (unsigned short*)(W + OFF_FW2H);
    unsigned short* fw2l  = (unsigned short*)(W + OFF_FW2L);
    unsigned short* kwth  = (unsigned short*)(W + OFF_KWTH);
    unsigned short* kwtl  = (unsigned short*)(W + OFF_KWTL);
    unsigned short* m2th  = (unsigned short*)(W + OFF_M2);
    unsigned short* m2tl  = (unsigned short*)(W + OFF_M2 + 524288ull);
    float*          m2p   = (float*)(W + OFF_M2P);
    float*          pkp   = (float*)(W + OFF_PKP);
    float*          b2    = (float*)(W + OFF_B2);
    unsigned short* featsb= (unsigned short*)(W + OFF_FEATS);
    float*          pkbuf = (float*)(W + OFF_PK);
    unsigned short* h1    = (unsigned short*)(W + OFF_H1);
    unsigned short* h2    = (unsigned short*)(W + OFF_H2);
    float*          pf    = (float*)(W + OFF_PF);
    unsigned short* ew1t  = (unsigned short*)(W + OFF_EW1T);
    unsigned short* ew2t  = (unsigned short*)(W + OFF_EW2T);
    unsigned short* ew3t  = (unsigned short*)(W + OFF_EW3T);
    float*          wslot = (float*)(W + OFF_WSL);
    int*            rowsl = (int*)(W + OFF_RSL);
    int*            sl    = (int*)(W + OFF_SL);
    int*            top_e = (int*)(W + OFF_TOPE);
    float*          top_w = (float*)(W + OFF_TOPW);
    int*            cnt   = (int*)(W + OFF_CNT);
    int*            cnt2  = cnt + 8;
    int*            offs  = cnt + 16;

    float* outF = (float*)d_out;
    float* outW = outF + 8192000;
    float* outT = outF + 8257536;
    float* outS = outF + 8273920;

    // outF/outT/outS are fully written by k_combine/k_route; only outW is scattered.
    hipMemsetAsync(outW, 0, 65536 * sizeof(float), stream);
    hipMemsetAsync(W + OFF_CNT, 0, 256, stream);

    // conversions / transposes (ws is re-poisoned every call; must redo each launch)
    k_split_convert<<<dim3((BB * DD) / 1024), 256, 0, stream>>>(x, x_hi, x_lo, BB * DD);
    k_split_convert<<<dim3((HH * HH) / 1024), 256, 0, stream>>>(fw2, fw2h, fw2l, HH * HH);
    k_transpose<true ><<<dim3(128 / 32, HH / 32, 1), 256, 0, stream>>>(kw, kwth, kwtl, HH, 128, 128);
    k_transpose<true ><<<dim3(HH / 32, DD / 32, 1), 256, 0, stream>>>(fw1, w1th, w1tl, DD, HH, HH);
    k_transpose<false><<<dim3(HH / 32, HH / 32, 1), 256, 0, stream>>>(fw2, w2t, nullptr, HH, HH, HH);
    k_transpose<false><<<dim3(HH / 32, HH / 32, EE), 256, 0, stream>>>(ew1, ew1t, nullptr, HH, HH, HH);
    k_transpose<false><<<dim3(HM / 32, HH / 32, EE), 256, 0, stream>>>(ew2, ew2t, nullptr, HH, HM, HM);
    k_transpose<false><<<dim3(CP / 32, HM / 32, EE), 256, 0, stream>>>(ew3, ew3t, nullptr, HM, CC, CP);

    // M2 = fw2 @ kw  (3-term split MFMA, split-K=8, then reduce+transpose+split)
    k_split3<<<dim3(HH / 128, 8), 256, 0, stream>>>(fw2h, fw2l, kwth, kwtl, m2p, HH, HH / 8);
    k_m2red<<<dim3(HH / 32, 128 / 32), 256, 0, stream>>>(m2p, m2th, m2tl);
    k_bias2<<<dim3(128), 64, 0, stream>>>(fb2, kw, kb, b2);

    // features
    k_l1<<<dim3(BB / 128, HH / 128), 256, 0, stream>>>(x_hi, x_lo, w1th, w1tl, fb1, hph, hpl);
    k_l2<<<dim3(BB / 256, HH / 256), 512, 0, stream>>>(hph, w2t, fb2, featsb);

    // pk = hpre @ M2 (3-term split MFMA, split-K=4, then reduce + bias)
    k_split3<<<dim3(BB / 128, 4), 256, 0, stream>>>(hph, hpl, m2th, m2tl, pkp, HH, HH / 4);
    k_pkred<<<dim3((BB * 128) / 256), 256, 0, stream>>>(pkp, b2, pkbuf);

    // routing
    k_route<<<dim3(BB), 64, 0, stream>>>(pkbuf, keys, outW, outT, outS, top_e, top_w, cnt);
    // pkbuf is dead now; zero the slot arrays that alias it (pad slots -> b=0, w=0)
    hipMemsetAsync(W + OFF_WSL, 0, 147456, stream);
    k_offs<<<1, 1, 0, stream>>>(cnt, offs);
    k_scatter<<<dim3(BB / 256), 256, 0, stream>>>(top_e, top_w, offs, cnt2, rowsl, wslot, sl);

    // experts (top-2 only); L1 gathers feats rows in-GEMM via rowslot
    k_le<true , 4><<<dim3(NT2, HH / 256), 512, 0, stream>>>(featsb, ew1t, eb1, h1, offs, rowsl, HH, HH);
    k_le<false, 2><<<dim3(NT2, HM / 128), 512, 0, stream>>>(h1, ew2t, eb2, h2, offs, nullptr, HM, HH);
    // final: weighted per-slot partial (pf aliases h1, dead after expert L2), then combine
    k_final<<<dim3(NT2, CP / 128), 512, 0, stream>>>(h2, ew3t, eb3, pf, offs, wslot);
    k_combine<<<dim3(BB), 256, 0, stream>>>(pf, sl, outF);
}

// Round 8
// 1312.189 us; speedup vs baseline: 2.2237x; 2.2237x over previous
//
#include <hip/hip_runtime.h>

// ---------- types / helpers ----------
typedef __attribute__((ext_vector_type(8))) short short8;   // 8 x bf16 bits
typedef __attribute__((ext_vector_type(4))) float float4v;
typedef __attribute__((ext_vector_type(4))) unsigned short u16x4;

__device__ __forceinline__ float bf2f(unsigned short u) {
    union { unsigned int i; float f; } v; v.i = ((unsigned int)u) << 16; return v.f;
}
__device__ __forceinline__ unsigned short f2bf(float f) {   // round-to-nearest-even
    union { float f; unsigned int u; } v; v.f = f;
    unsigned int u = v.u;
    return (unsigned short)((u + 0x7fffu + ((u >> 16) & 1u)) >> 16);
}
__device__ __forceinline__ void load_lds16(const void* g, void* l) {
    __builtin_amdgcn_global_load_lds((const __attribute__((address_space(1))) void*)g,
                                     (__attribute__((address_space(3))) void*)l, 16, 0, 0);
}
__device__ __forceinline__ float wred(float v) {
#pragma unroll
    for (int o = 32; o > 0; o >>= 1) v += __shfl_down(v, o);
    return __shfl(v, 0);
}

// ---------- problem dims ----------
#define BB 8192
#define DD 1024
#define HH 2048
#define HM 1024
#define CC 1000
#define CP 1024
#define EE 8
#define CAP2 18432          // 72 row tiles of 256 (expert capacity, 256-padded)
#define NT2 72

// ---------- ws layout (bytes) ----------
#define OFF_XHI   0ull
#define OFF_XLO   16777216ull
#define OFF_W1TH  33554432ull
#define OFF_W1TL  37748736ull
#define OFF_W2T   41943040ull
#define OFF_HPH   50331648ull   // ends 83886080
#define OFF_HPL   83886080ull   // ends 117440512
#define OFF_M2    117440512ull  // m2th (0.5MB) + m2tl (0.5MB)
#define OFF_B2    118489088ull
#define OFF_FEATS 118490112ull  // bf16 feats, ends 152044544 (LIVE through expert L1)
#define OFF_PK    152044544ull  // ends 156238848 (kwt hi/lo early, pkbuf mid, slots late)
#define OFF_H1    0ull          // alias: x/w1t/w2t/hph region — dead after pk split3; 75.5MB
#define OFF_EW1T  156238848ull  // ends 223347712
#define OFF_H2    156238848ull  // alias ew1T (dead after expert L1); 37.7MB
#define OFF_EW2T  223347712ull
#define OFF_EW3T  256902144ull
#define OFF_TOPE  273818624ull
#define OFF_TOPW  273884160ull
#define OFF_CNT   273949696ull
// aliases
#define OFF_FW2H  OFF_HPH                  // 8.4MB, dead before l1 writes hph
#define OFF_FW2L  (OFF_HPH + 8388608ull)
#define OFF_KWTH  OFF_PK                   // 0.5MB, dead before pkred writes pkbuf
#define OFF_KWTL  (OFF_PK + 524288ull)
#define OFF_M2P   OFF_FEATS                // 8MB partials, dead before l2 writes feats
#define OFF_PKP   0ull                     // 16.8MB partials, dead before h1 written
#define OFF_WSL   OFF_PK                   // wslot[18432] f32 — pkbuf dead after k_route
#define OFF_RSL   (OFF_PK + 73728ull)      // rowslot[18432] i32
#define OFF_SL    (OFF_PK + 147456ull)     // sl[16384] i32: b -> its two slots
#define OFF_PF    0ull                     // pf[CAP2][CP] f32 (75.5MB) — aliases h1 (dead after expert L2)

// ---------- XCD-chunked grid swizzle ----------
#define SWZ_G 4
__device__ __forceinline__ void remap_xy(int& x, int& y) {
    const int nbx = gridDim.x, nby = gridDim.y;
    int lin = blockIdx.y * nbx + blockIdx.x;
    int xcd = lin & 7, idx = lin >> 3;
    int rpx = nbx >> 3;                 // row-tiles per xcd
    int gs  = rpx * SWZ_G;              // blocks per col-group within chunk
    int grp = idx / gs, wi = idx - grp * gs;
    int xl  = wi / SWZ_G, yl = wi - xl * SWZ_G;
    x = xcd * rpx + xl;
    y = grp * SWZ_G + yl;
}

// ---------- conversion kernels ----------
__global__ __launch_bounds__(256) void k_split_convert(const float* __restrict__ in,
    unsigned short* __restrict__ hi, unsigned short* __restrict__ lo, int n)
{
    int i = (blockIdx.x * 256 + threadIdx.x) * 4;
    if (i >= n) return;
    float4 v = *(const float4*)(in + i);
    unsigned short h0 = f2bf(v.x), h1 = f2bf(v.y), h2 = f2bf(v.z), h3 = f2bf(v.w);
    u16x4 hv = {h0, h1, h2, h3};
    u16x4 lv = {f2bf(v.x - bf2f(h0)), f2bf(v.y - bf2f(h1)),
                f2bf(v.z - bf2f(h2)), f2bf(v.w - bf2f(h3))};
    *(u16x4*)(hi + i) = hv;
    *(u16x4*)(lo + i) = lv;
}

// out[b][n][k] = in[b][k][n]  (bf16, zero-pad n >= N up to Npad)
template<bool SPLIT>
__global__ __launch_bounds__(256) void k_transpose(const float* __restrict__ in,
    unsigned short* __restrict__ hi, unsigned short* __restrict__ lo, int K, int N, int Npad)
{
    __shared__ float tile[32][33];
    const float* src = in + (size_t)blockIdx.z * K * N;
    int n0 = blockIdx.x * 32, k0 = blockIdx.y * 32;
    int tx = threadIdx.x & 31, ty = threadIdx.x >> 5;
#pragma unroll
    for (int r = ty; r < 32; r += 8) {
        int n = n0 + tx;
        tile[r][tx] = (n < N) ? src[(size_t)(k0 + r) * N + n] : 0.f;
    }
    __syncthreads();
    size_t ob = (size_t)blockIdx.z * Npad * K;
    {
        int n  = threadIdx.x >> 3;          // 0..31  (output row within tile)
        int kq = (threadIdx.x & 7) * 4;     // 0..28  (output col quad, contiguous in K)
        u16x4 hv, lv;
#pragma unroll
        for (int i = 0; i < 4; ++i) {
            float v = tile[kq + i][n];
            unsigned short h = f2bf(v);
            hv[i] = h;
            lv[i] = SPLIT ? f2bf(v - bf2f(h)) : (unsigned short)0;
        }
        size_t o = ob + (size_t)(n0 + n) * K + k0 + kq;
        *(u16x4*)(hi + o) = hv;
        if (SPLIT) *(u16x4*)(lo + o) = lv;
    }
}

// ============================================================================
// BK=64 4-phase core (kept for k_l2 only: grid=256 is perfectly packed at 1/CU)
// ============================================================================
template<int NB>
__device__ __forceinline__ void gemm256(
    const unsigned short* __restrict__ a0, const unsigned short* __restrict__ a1,
    const unsigned short* __restrict__ b0, const unsigned short* __restrict__ b1,
    int K, unsigned short* L, float4v (&acc)[8][NB])
{
    const int tid = threadIdx.x;
    const int lane = tid & 63, w = tid >> 6;
    const int lrow = lane & 15, quad = (lane >> 4) & 3;
    const int wm = w >> 2, wn = w & 3;
    const int NT = K >> 6;
    constexpr int BSH  = NB * 2048;         // B half-tile shorts
    constexpr int BUFS = 16384 + 2 * BSH;   // per-buffer shorts
    constexpr int VM   = (NB == 4) ? 6 : 4; // steady-state vmcnt

    int aoff[8], boff[NB];
#pragma unroll
    for (int i = 0; i < 8; ++i) {
        int r = wm * 128 + i * 16 + lrow;
        aoff[i] = r * 32 + (quad ^ ((r >> 1) & 3)) * 8;
    }
#pragma unroll
    for (int j = 0; j < NB; ++j) {
        int r = wn * (NB * 16) + j * 16 + lrow;
        boff[j] = r * 32 + (quad ^ ((r >> 1) & 3)) * 8;
    }
    unsigned short* const dA = L + w * 512;
    unsigned short* const dB = L + 16384 + w * 512;

    auto stgA = [&](int t, int kh, int buf) {
        unsigned short* d = dA + buf * BUFS + kh * 8192;
        const int ko = t * 64 + kh * 32;
        load_lds16(a0 + ko, d);
        load_lds16(a1 + ko, d + 4096);
    };
    auto stgB = [&](int t, int kh, int buf) {
        unsigned short* d = dB + buf * BUFS + kh * BSH;
        const int ko = t * 64 + kh * 32;
        load_lds16(b0 + ko, d);
        if constexpr (NB == 4) load_lds16(b1 + ko, d + 4096);
    };

    stgA(0, 0, 0); stgA(0, 1, 0); stgB(0, 0, 0); stgB(0, 1, 0);
    if (NT > 1) { stgB(1, 0, 1); stgA(1, 0, 1); stgB(1, 1, 1); }
    asm volatile("s_waitcnt vmcnt(%0)" :: "i"(VM) : "memory");
    __builtin_amdgcn_s_barrier();

    short8 af[4], bfr[NB];
    for (int t = 0; t < NT; ++t) {
        const int buf = t & 1;
        const unsigned short* Lb = L + buf * BUFS;
        // ---- P1: M-lo, k0 ----
#pragma unroll
        for (int i = 0; i < 4; ++i) af[i]  = *(const short8*)(Lb + aoff[i]);
#pragma unroll
        for (int j = 0; j < NB; ++j) bfr[j] = *(const short8*)(Lb + 16384 + boff[j]);
        if (t + 1 < NT) stgA(t + 1, 1, buf ^ 1);
        __builtin_amdgcn_s_barrier();
        __builtin_amdgcn_s_setprio(1);
#pragma unroll
        for (int i = 0; i < 4; ++i)
#pragma unroll
            for (int j = 0; j < NB; ++j)
                acc[i][j] = __builtin_amdgcn_mfma_f32_16x16x32_bf16(af[i], bfr[j], acc[i][j], 0, 0, 0);
        __builtin_amdgcn_s_setprio(0);
        __builtin_amdgcn_s_barrier();
        // ---- P2: M-hi, k0 ----
#pragma unroll
        for (int i = 0; i < 4; ++i) af[i] = *(const short8*)(Lb + aoff[4 + i]);
        if (t + 2 < NT) stgB(t + 2, 0, buf);
        __builtin_amdgcn_s_barrier();
        __builtin_amdgcn_s_setprio(1);
#pragma unroll
        for (int i = 0; i < 4; ++i)
#pragma unroll
            for (int j = 0; j < NB; ++j)
                acc[4 + i][j] = __builtin_amdgcn_mfma_f32_16x16x32_bf16(af[i], bfr[j], acc[4 + i][j], 0, 0, 0);
        __builtin_amdgcn_s_setprio(0);
        __builtin_amdgcn_s_barrier();
        // ---- P3: M-lo, k1 ----
#pragma unroll
        for (int i = 0; i < 4; ++i) af[i]  = *(const short8*)(Lb + 8192 + aoff[i]);
#pragma unroll
        for (int j = 0; j < NB; ++j) bfr[j] = *(const short8*)(Lb + 16384 + BSH + boff[j]);
        if (t + 2 < NT) stgA(t + 2, 0, buf);
        __builtin_amdgcn_s_barrier();
        __builtin_amdgcn_s_setprio(1);
#pragma unroll
        for (int i = 0; i < 4; ++i)
#pragma unroll
            for (int j = 0; j < NB; ++j)
                acc[i][j] = __builtin_amdgcn_mfma_f32_16x16x32_bf16(af[i], bfr[j], acc[i][j], 0, 0, 0);
        __builtin_amdgcn_s_setprio(0);
        __builtin_amdgcn_s_barrier();
        // ---- P4: M-hi, k1 ----
#pragma unroll
        for (int i = 0; i < 4; ++i) af[i] = *(const short8*)(Lb + 8192 + aoff[4 + i]);
        if (t + 2 < NT) {
            stgB(t + 2, 1, buf);
            asm volatile("s_waitcnt vmcnt(%0)" :: "i"(VM) : "memory");
        } else {
            asm volatile("s_waitcnt vmcnt(0)" ::: "memory");
        }
        __builtin_amdgcn_s_barrier();
        __builtin_amdgcn_s_setprio(1);
#pragma unroll
        for (int i = 0; i < 4; ++i)
#pragma unroll
            for (int j = 0; j < NB; ++j)
                acc[4 + i][j] = __builtin_amdgcn_mfma_f32_16x16x32_bf16(af[i], bfr[j], acc[4 + i][j], 0, 0, 0);
        __builtin_amdgcn_s_setprio(0);
        __builtin_amdgcn_s_barrier();
    }
}

// ============================================================================
// BK=32 2-phase core, half LDS -> 2 blocks/CU. 512 thr = 8 waves (2M x 4N).
// LDS/buf: A 256x32 (8192 sh) + B NB*64 x 32 (NB*2048 sh); x2 buf = 64KB (NB=4)
// / 48KB (NB=2). Per tile: stage ALL of tile t+1 -> buf^1 (top), P1 Mlo, P2 Mhi,
// vmcnt(0), ONE barrier. 32 MFMA/barrier at NB=4.
// sched_barrier(0) after every s_barrier / before it: raw s_barrier is NOT a
// compiler memory fence (rule #18) — pins LDS reads / global_load_lds on the
// correct side. Validated correct in R7 (passed, absmax unchanged).
// R8 FIX: launch_bounds 2nd arg empirically acts as BLOCKS/CU on this
// toolchain — (512,4) capped VGPR at 64 and spilled acc to scratch (R7:
// VGPR=64, WRITE_SIZE 3.97GB, 2195us). (512,2) -> cap 128, VGPR ~92, no
// spill; LDS footprint alone gives the intended 2 blocks/CU.
// ============================================================================
template<int NB>
__device__ __forceinline__ void gemm256b(
    const unsigned short* __restrict__ a0, const unsigned short* __restrict__ a1,
    const unsigned short* __restrict__ b0, const unsigned short* __restrict__ b1,
    int K, unsigned short* L, float4v (&acc)[8][NB])
{
    const int tid = threadIdx.x;
    const int lane = tid & 63, w = tid >> 6;
    const int lrow = lane & 15, quad = (lane >> 4) & 3;
    const int wm = w >> 2, wn = w & 3;
    const int NT = K >> 5;
    constexpr int BUFS = 8192 + NB * 2048;  // per-buffer shorts

    int aoff[8], boff[NB];
#pragma unroll
    for (int i = 0; i < 8; ++i) {
        int r = wm * 128 + i * 16 + lrow;
        aoff[i] = r * 32 + (quad ^ ((r >> 1) & 3)) * 8;
    }
#pragma unroll
    for (int j = 0; j < NB; ++j) {
        int r = wn * (NB * 16) + j * 16 + lrow;
        boff[j] = r * 32 + (quad ^ ((r >> 1) & 3)) * 8;
    }
    unsigned short* const dA = L + w * 512;
    unsigned short* const dB = L + 8192 + w * 512;

    auto stg = [&](int t, int buf) {            // stage full K-tile t (A + B)
        unsigned short* da = dA + buf * BUFS;
        unsigned short* db = dB + buf * BUFS;
        const int ko = t * 32;
        load_lds16(a0 + ko, da);                // M-lo rows
        load_lds16(a1 + ko, da + 4096);         // M-hi rows
        load_lds16(b0 + ko, db);
        if constexpr (NB == 4) load_lds16(b1 + ko, db + 4096);
    };

    // prologue: tile 0
    stg(0, 0);
    asm volatile("s_waitcnt vmcnt(0)" ::: "memory");
    __builtin_amdgcn_sched_barrier(0);
    __builtin_amdgcn_s_barrier();
    __builtin_amdgcn_sched_barrier(0);

    short8 af[4], bfr[NB];
    for (int t = 0; t < NT; ++t) {
        const int buf = t & 1;
        const unsigned short* Lb = L + buf * BUFS;
        if (t + 1 < NT) stg(t + 1, buf ^ 1);    // issue early: full tile to land
        // ---- P1: M-lo ----
#pragma unroll
        for (int i = 0; i < 4; ++i) af[i]  = *(const short8*)(Lb + aoff[i]);
#pragma unroll
        for (int j = 0; j < NB; ++j) bfr[j] = *(const short8*)(Lb + 8192 + boff[j]);
        __builtin_amdgcn_s_setprio(1);
#pragma unroll
        for (int i = 0; i < 4; ++i)
#pragma unroll
            for (int j = 0; j < NB; ++j)
                acc[i][j] = __builtin_amdgcn_mfma_f32_16x16x32_bf16(af[i], bfr[j], acc[i][j], 0, 0, 0);
        __builtin_amdgcn_s_setprio(0);
        // ---- P2: M-hi (reuse bfr) ----
#pragma unroll
        for (int i = 0; i < 4; ++i) af[i] = *(const short8*)(Lb + aoff[4 + i]);
        __builtin_amdgcn_s_setprio(1);
#pragma unroll
        for (int i = 0; i < 4; ++i)
#pragma unroll
            for (int j = 0; j < NB; ++j)
                acc[4 + i][j] = __builtin_amdgcn_mfma_f32_16x16x32_bf16(af[i], bfr[j], acc[4 + i][j], 0, 0, 0);
        __builtin_amdgcn_s_setprio(0);
        asm volatile("s_waitcnt vmcnt(0)" ::: "memory");
        __builtin_amdgcn_sched_barrier(0);
        __builtin_amdgcn_s_barrier();
        __builtin_amdgcn_sched_barrier(0);
    }
}

// ---------- layer 1: split (bf16x2) GEMM, relu, split-store (128^2 structure) ----------
__global__ __launch_bounds__(256, 2) void k_l1(
    const unsigned short* __restrict__ xh, const unsigned short* __restrict__ xl,
    const unsigned short* __restrict__ wh, const unsigned short* __restrict__ wl,
    const float* __restrict__ bias, unsigned short* __restrict__ oh, unsigned short* __restrict__ ol)
{
    __shared__ __align__(16) unsigned short Ash[4096], Asl[4096], Bsh[4096], Bsl[4096];
    const int K = DD, N = HH;
    int bx, by; remap_xy(bx, by);
    const int row0 = bx * 128, col0 = by * 128;
    const int t = threadIdx.x, lane = t & 63, w = t >> 6;
    const int lrow = lane & 15, quad = lane >> 4;
    const int swz = (quad ^ ((lrow >> 1) & 3)) * 8;
    const int wr = (w & 1) * 64, wc = (w >> 1) * 64;
    float4v acc[4][4] = {};
    for (int k0 = 0; k0 < K; k0 += 32) {
#pragma unroll
        for (int p = 0; p < 2; ++p) {
            int c = p * 256 + t;
            int r = c >> 2, q = (c & 3) ^ ((r >> 1) & 3);
            size_t ga = (size_t)(row0 + r) * K + k0 + q * 8;
            size_t gb = (size_t)(col0 + r) * K + k0 + q * 8;
            int lo_ = (p * 256 + w * 64) * 8;
            load_lds16(xh + ga, Ash + lo_);
            load_lds16(xl + ga, Asl + lo_);
            load_lds16(wh + gb, Bsh + lo_);
            load_lds16(wl + gb, Bsl + lo_);
        }
        __syncthreads();
        short8 ah[4], al[4], bh[4], bl[4];
#pragma unroll
        for (int i = 0; i < 4; ++i) {
            int o = (wr + i * 16 + lrow) * 32 + swz;
            ah[i] = *(const short8*)(Ash + o);
            al[i] = *(const short8*)(Asl + o);
        }
#pragma unroll
        for (int j = 0; j < 4; ++j) {
            int o = (wc + j * 16 + lrow) * 32 + swz;
            bh[j] = *(const short8*)(Bsh + o);
            bl[j] = *(const short8*)(Bsl + o);
        }
#pragma unroll
        for (int i = 0; i < 4; ++i)
#pragma unroll
            for (int j = 0; j < 4; ++j) {
                float4v a0 = __builtin_amdgcn_mfma_f32_16x16x32_bf16(al[i], bh[j], acc[i][j], 0, 0, 0);
                a0 = __builtin_amdgcn_mfma_f32_16x16x32_bf16(ah[i], bl[j], a0, 0, 0, 0);
                acc[i][j] = __builtin_amdgcn_mfma_f32_16x16x32_bf16(ah[i], bh[j], a0, 0, 0, 0);
            }
        __syncthreads();
    }
#pragma unroll
    for (int i = 0; i < 4; ++i)
#pragma unroll
        for (int r = 0; r < 4; ++r) {
            int row = row0 + wr + i * 16 + quad * 4 + r;
            size_t base = (size_t)row * N;
#pragma unroll
            for (int j = 0; j < 4; ++j) {
                int col = col0 + wc + j * 16 + lrow;
                float v = fmaxf(acc[i][j][r] + bias[col], 0.f);
                unsigned short h = f2bf(v);
                oh[base + col] = h;
                ol[base + col] = f2bf(v - bf2f(h));
            }
        }
}

// ---------- generic 3-term split GEMM, N=128, split-K, fp32 partial out ----------
__global__ __launch_bounds__(256, 2) void k_split3(
    const unsigned short* __restrict__ ah_, const unsigned short* __restrict__ al_,
    const unsigned short* __restrict__ bh_, const unsigned short* __restrict__ bl_,
    float* __restrict__ out, int K, int klen)
{
    __shared__ __align__(16) unsigned short Ash[4096], Asl[4096], Bsh[4096], Bsl[4096];
    const int row0 = blockIdx.x * 128;
    const int kb = blockIdx.y * klen;
    out += (size_t)blockIdx.y * gridDim.x * 128 * 128;
    const int t = threadIdx.x, lane = t & 63, w = t >> 6;
    const int lrow = lane & 15, quad = lane >> 4;
    const int swz = (quad ^ ((lrow >> 1) & 3)) * 8;
    const int wr = (w & 1) * 64, wc = (w >> 1) * 64;
    float4v acc[4][4] = {};
    for (int k0 = kb; k0 < kb + klen; k0 += 32) {
#pragma unroll
        for (int p = 0; p < 2; ++p) {
            int c = p * 256 + t;
            int r = c >> 2, q = (c & 3) ^ ((r >> 1) & 3);
            size_t ga = (size_t)(row0 + r) * K + k0 + q * 8;
            size_t gb = (size_t)r * K + k0 + q * 8;           // B has exactly 128 rows
            int lo_ = (p * 256 + w * 64) * 8;
            load_lds16(ah_ + ga, Ash + lo_);
            load_lds16(al_ + ga, Asl + lo_);
            load_lds16(bh_ + gb, Bsh + lo_);
            load_lds16(bl_ + gb, Bsl + lo_);
        }
        __syncthreads();
        short8 ah[4], al[4], bh[4], bl[4];
#pragma unroll
        for (int i = 0; i < 4; ++i) {
            int o = (wr + i * 16 + lrow) * 32 + swz;
            ah[i] = *(const short8*)(Ash + o);
            al[i] = *(const short8*)(Asl + o);
        }
#pragma unroll
        for (int j = 0; j < 4; ++j) {
            int o = (wc + j * 16 + lrow) * 32 + swz;
            bh[j] = *(const short8*)(Bsh + o);
            bl[j] = *(const short8*)(Bsl + o);
        }
#pragma unroll
        for (int i = 0; i < 4; ++i)
#pragma unroll
            for (int j = 0; j < 4; ++j) {
                float4v a0 = __builtin_amdgcn_mfma_f32_16x16x32_bf16(al[i], bh[j], acc[i][j], 0, 0, 0);
                a0 = __builtin_amdgcn_mfma_f32_16x16x32_bf16(ah[i], bl[j], a0, 0, 0, 0);
                acc[i][j] = __builtin_amdgcn_mfma_f32_16x16x32_bf16(ah[i], bh[j], a0, 0, 0, 0);
            }
        __syncthreads();
    }
#pragma unroll
    for (int i = 0; i < 4; ++i)
#pragma unroll
        for (int r = 0; r < 4; ++r) {
            int row = row0 + wr + i * 16 + quad * 4 + r;
            size_t base = (size_t)row * 128;
#pragma unroll
            for (int j = 0; j < 4; ++j) {
                int col = wc + j * 16 + lrow;
                out[base + col] = acc[i][j][r];
            }
        }
}

// ---------- M2 reduce: sum 8 partials, transpose, split to bf16 hi/lo ----------
__global__ __launch_bounds__(256) void k_m2red(const float* __restrict__ p,
    unsigned short* __restrict__ th, unsigned short* __restrict__ tl)
{
    __shared__ float tile[32][33];
    const int h0 = blockIdx.x * 32, c0 = blockIdx.y * 32;
    const int t = threadIdx.x;
    {
        int r = t >> 3, cq = (t & 7) * 4;
        size_t base = (size_t)(h0 + r) * 128 + c0 + cq;
        float4 s = *(const float4*)(p + base);
#pragma unroll
        for (int ks = 1; ks < 8; ++ks) {
            float4 v = *(const float4*)(p + (size_t)ks * HH * 128 + base);
            s.x += v.x; s.y += v.y; s.z += v.z; s.w += v.w;
        }
        tile[r][cq] = s.x; tile[r][cq + 1] = s.y; tile[r][cq + 2] = s.z; tile[r][cq + 3] = s.w;
    }
    __syncthreads();
    {
        int cr = t >> 3, hq = (t & 7) * 4;
        u16x4 hv, lv;
#pragma unroll
        for (int i = 0; i < 4; ++i) {
            float v = tile[hq + i][cr];
            unsigned short h = f2bf(v);
            hv[i] = h; lv[i] = f2bf(v - bf2f(h));
        }
        size_t o = (size_t)(c0 + cr) * HH + h0 + hq;
        *(u16x4*)(th + o) = hv;
        *(u16x4*)(tl + o) = lv;
    }
}

// ---------- pk reduce: sum 4 partials + bias ----------
__global__ __launch_bounds__(256) void k_pkred(const float* __restrict__ p,
    const float* __restrict__ b2, float* __restrict__ out)
{
    int idx = blockIdx.x * 256 + threadIdx.x;
    const size_t S = (size_t)BB * 128;
    out[idx] = p[idx] + p[idx + S] + p[idx + 2 * S] + p[idx + 3 * S] + b2[idx & 127];
}

// ---------- layer 2: single bf16 GEMM -> feats bf16 (no relu), 256^2 BK=64 ----------
__global__ __launch_bounds__(512, 2) void k_l2(const unsigned short* __restrict__ A,
    const unsigned short* __restrict__ Bt, const float* __restrict__ bias,
    unsigned short* __restrict__ outb)
{
    __shared__ __align__(16) unsigned short L[65536];
    const int K = HH, N = HH;
    int bx, by; remap_xy(bx, by);
    const int row0 = bx * 256, col0 = by * 256;
    const int tid = threadIdx.x;
    const int r0 = tid >> 2, c0 = tid & 3;
    const int csw = (c0 ^ ((r0 >> 1) & 3)) * 8;
    const unsigned short* a0 = A + (size_t)(row0 + r0) * K + csw;
    const unsigned short* a1 = a0 + (size_t)128 * K;
    const unsigned short* b0 = Bt + (size_t)(col0 + r0) * K + csw;
    const unsigned short* b1 = b0 + (size_t)128 * K;
    float4v acc[8][4] = {};
    gemm256<4>(a0, a1, b0, b1, K, L, acc);
    const int lane = tid & 63, w = tid >> 6;
    const int lrow = lane & 15, quad = (lane >> 4) & 3;
    const int wm = w >> 2, wn = w & 3;
#pragma unroll
    for (int ii = 0; ii < 8; ++ii)
#pragma unroll
        for (int rr = 0; rr < 4; ++rr) {
            int row = row0 + wm * 128 + ii * 16 + quad * 4 + rr;
            size_t base = (size_t)row * N;
#pragma unroll
            for (int j = 0; j < 4; ++j) {
                int col = col0 + wn * 64 + j * 16 + lrow;
                outb[base + col] = f2bf(acc[ii][j][rr] + bias[col]);
            }
        }
}

// ---------- expert GEMM (relu, bf16 out), 256xBN BK=32 2/CU; IND: rows via rowslot ----------
template<bool IND, int NB>
__global__ __launch_bounds__(512, 2) void k_le(const unsigned short* __restrict__ A,
    const unsigned short* __restrict__ WT, const float* __restrict__ bias,
    unsigned short* __restrict__ out, const int* __restrict__ offs,
    const int* __restrict__ rowslot, int N, int K)
{
    __shared__ __align__(16) unsigned short L[2 * (8192 + NB * 2048)];
    int bx, by; remap_xy(bx, by);
    const int row0 = bx * 256;
    if (row0 >= offs[8]) return;
    int e = 0;
#pragma unroll
    for (int i = 1; i < 8; ++i) if (offs[i] <= row0) e = i;
    const unsigned short* Bt = WT + (size_t)e * N * K;
    const float* bs = bias + (size_t)e * N;
    const int col0 = by * (NB * 64);
    const int tid = threadIdx.x;
    const int r0 = tid >> 2, c0 = tid & 3;
    const int csw = (c0 ^ ((r0 >> 1) & 3)) * 8;
    const int gr0 = IND ? rowslot[row0 + r0] : (row0 + r0);
    const int gr1 = IND ? rowslot[row0 + 128 + r0] : (row0 + 128 + r0);
    const unsigned short* a0 = A + (size_t)gr0 * K + csw;
    const unsigned short* a1 = A + (size_t)gr1 * K + csw;
    const unsigned short* b0 = Bt + (size_t)(col0 + r0) * K + csw;
    const unsigned short* b1 = b0 + (size_t)128 * K;
    float4v acc[8][NB] = {};
    gemm256b<NB>(a0, a1, b0, b1, K, L, acc);
    const int lane = tid & 63, w = tid >> 6;
    const int lrow = lane & 15, quad = (lane >> 4) & 3;
    const int wm = w >> 2, wn = w & 3;
#pragma unroll
    for (int ii = 0; ii < 8; ++ii)
#pragma unroll
        for (int rr = 0; rr < 4; ++rr) {
            int row = row0 + wm * 128 + ii * 16 + quad * 4 + rr;
            size_t base = (size_t)row * N;
#pragma unroll
            for (int j = 0; j < NB; ++j) {
                int col = col0 + wn * (NB * 16) + j * 16 + lrow;
                out[base + col] = f2bf(fmaxf(acc[ii][j][rr] + bs[col], 0.f));
            }
        }
}

// ---------- final expert GEMM: weighted per-slot partial (NO atomics), BK=32 ----------
__global__ __launch_bounds__(512, 2) void k_final(const unsigned short* __restrict__ A,
    const unsigned short* __restrict__ WT, const float* __restrict__ bias,
    float* __restrict__ pf, const int* __restrict__ offs,
    const float* __restrict__ wslot)
{
    constexpr int NB = 2;
    __shared__ __align__(16) unsigned short L[2 * (8192 + NB * 2048)];
    const int N = CP, K = HM;
    int bx, by; remap_xy(bx, by);
    const int row0 = bx * 256;
    if (row0 >= offs[8]) return;
    int e = 0;
#pragma unroll
    for (int i = 1; i < 8; ++i) if (offs[i] <= row0) e = i;
    const unsigned short* Bt = WT + (size_t)e * N * K;
    const float* bs = bias + (size_t)e * CC;
    const int col0 = by * (NB * 64);
    const int tid = threadIdx.x;
    const int r0 = tid >> 2, c0 = tid & 3;
    const int csw = (c0 ^ ((r0 >> 1) & 3)) * 8;
    const unsigned short* a0 = A + (size_t)(row0 + r0) * K + csw;
    const unsigned short* a1 = a0 + (size_t)128 * K;
    const unsigned short* b0 = Bt + (size_t)(col0 + r0) * K + csw;
    float4v acc[8][NB] = {};
    gemm256b<NB>(a0, a1, b0, b0, K, L, acc);
    const int lane = tid & 63, w = tid >> 6;
    const int lrow = lane & 15, quad = (lane >> 4) & 3;
    const int wm = w >> 2, wn = w & 3;
#pragma unroll
    for (int ii = 0; ii < 8; ++ii)
#pragma unroll
        for (int rr = 0; rr < 4; ++rr) {
            int row = row0 + wm * 128 + ii * 16 + quad * 4 + rr;
            float wv = wslot[row];
            if (wv != 0.f) {
                float* prow = pf + (size_t)row * CP;
#pragma unroll
                for (int j = 0; j < NB; ++j) {
                    int col = col0 + wn * (NB * 16) + j * 16 + lrow;
                    if (col < CC) prow[col] = wv * (acc[ii][j][rr] + bs[col]);
                }
            }
        }
}

// ---------- combine: outF[b][c] = pf[sl[2b]][c] + pf[sl[2b+1]][c] ----------
__global__ __launch_bounds__(256) void k_combine(const float* __restrict__ pf,
    const int* __restrict__ sl, float* __restrict__ outF)
{
    int b = blockIdx.x;
    int c = threadIdx.x * 4;
    if (c >= CC) return;
    int s0 = sl[b * 2], s1 = sl[b * 2 + 1];
    float4 v0 = *(const float4*)(pf + (size_t)s0 * CP + c);
    float4 v1 = *(const float4*)(pf + (size_t)s1 * CP + c);
    float4 r; r.x = v0.x + v1.x; r.y = v0.y + v1.y; r.z = v0.z + v1.z; r.w = v0.w + v1.w;
    *(float4*)(outF + (size_t)b * CC + c) = r;
}

// ---------- b2[c] = sum_j fb2[j]*kw[j,c] + kb[c] ----------
__global__ __launch_bounds__(64) void k_bias2(const float* __restrict__ fb2,
    const float* __restrict__ kw, const float* __restrict__ kb, float* __restrict__ b2)
{
    int c = blockIdx.x, lane = threadIdx.x;
    float s = 0.f;
    for (int j = lane; j < HH; j += 64) s += fb2[j] * kw[(size_t)j * 128 + c];
    s = wred(s);
    if (lane == 0) b2[c] = s + kb[c];
}

// ---------- routing ----------
__global__ __launch_bounds__(64) void k_route(const float* __restrict__ pk,
    const float* __restrict__ keys, float* __restrict__ wout, float* __restrict__ tout,
    float* __restrict__ simout, int* __restrict__ top_e, float* __restrict__ top_w,
    int* __restrict__ cnt)
{
    int b = blockIdx.x, lane = threadIdx.x;
    float2 v = *(const float2*)&pk[(size_t)b * 128 + lane * 2];
    float inv = 1.f / fmaxf(sqrtf(wred(v.x * v.x + v.y * v.y)), 1e-12f);
    float sims[8];
#pragma unroll
    for (int e = 0; e < 8; ++e) {
        float2 kv = *(const float2*)&keys[e * 128 + lane * 2];
        float kinv = 1.f / fmaxf(sqrtf(wred(kv.x * kv.x + kv.y * kv.y)), 1e-12f);
        float d = wred(v.x * kv.x + v.y * kv.y);
        sims[e] = d * inv * kinv;
    }
    if (lane == 0) {
        int i1 = 0; float v1 = sims[0];
#pragma unroll
        for (int e = 1; e < 8; ++e) if (sims[e] > v1) { v1 = sims[e]; i1 = e; }
        int i2 = -1; float v2 = -1e30f;
#pragma unroll
        for (int e = 0; e < 8; ++e) if (e != i1 && sims[e] > v2) { v2 = sims[e]; i2 = e; }
        float e2 = expf(v2 - v1);
        float w1 = 1.f / (1.f + e2), w2 = e2 / (1.f + e2);
#pragma unroll
        for (int e = 0; e < 8; ++e) simout[(size_t)b * 8 + e] = sims[e];
        wout[(size_t)b * 8 + i1] = w1;
        wout[(size_t)b * 8 + i2] = w2;
        tout[(size_t)b * 2] = (float)i1; tout[(size_t)b * 2 + 1] = (float)i2;
        top_e[b * 2] = i1; top_e[b * 2 + 1] = i2;
        top_w[b * 2] = w1; top_w[b * 2 + 1] = w2;
        atomicAdd(&cnt[i1], 1); atomicAdd(&cnt[i2], 1);
    }
}

__global__ void k_offs(const int* __restrict__ cnt, int* __restrict__ offs)
{
    if (threadIdx.x == 0) {
        int o = 0;
        for (int e = 0; e < 8; ++e) { offs[e] = o; o += ((cnt[e] + 255) >> 8) << 8; }
        offs[8] = o;
    }
}

__global__ __launch_bounds__(256) void k_scatter(const int* __restrict__ top_e,
    const float* __restrict__ top_w, const int* __restrict__ offs, int* __restrict__ cnt2,
    int* __restrict__ rowslot, float* __restrict__ wslot, int* __restrict__ sl)
{
    int b = blockIdx.x * 256 + threadIdx.x;
    if (b >= BB) return;
#pragma unroll
    for (int j = 0; j < 2; ++j) {
        int e = top_e[b * 2 + j];
        int idx = atomicAdd(&cnt2[e], 1);
        int s = offs[e] + idx;
        rowslot[s] = b;
        wslot[s] = top_w[b * 2 + j];
        sl[b * 2 + j] = s;
    }
}

// ---------- launch ----------
extern "C" void kernel_launch(void* const* d_in, const int* in_sizes, int n_in,
                              void* d_out, int out_size, void* d_ws, size_t ws_size,
                              hipStream_t stream)
{
    const float* x    = (const float*)d_in[0];
    const float* fw1  = (const float*)d_in[1];
    const float* fb1  = (const float*)d_in[2];
    const float* fw2  = (const float*)d_in[3];
    const float* fb2  = (const float*)d_in[4];
    const float* kw   = (const float*)d_in[5];
    const float* kb   = (const float*)d_in[6];
    const float* keys = (const float*)d_in[7];
    const float* ew1  = (const float*)d_in[8];
    const float* eb1  = (const float*)d_in[9];
    const float* ew2  = (const float*)d_in[10];
    const float* eb2  = (const float*)d_in[11];
    const float* ew3  = (const float*)d_in[12];
    const float* eb3  = (const float*)d_in[13];

    char* W = (char*)d_ws;
    unsigned short* x_hi  = (unsigned short*)(W + OFF_XHI);
    unsigned short* x_lo  = (unsigned short*)(W + OFF_XLO);
    unsigned short* w1th  = (unsigned short*)(W + OFF_W1TH);
    unsigned short* w1tl  = (unsigned short*)(W + OFF_W1TL);
    unsigned short* w2t   = (unsigned short*)(W + OFF_W2T);
    unsigned short* hph   = (unsigned short*)(W + OFF_HPH);
    unsigned short* hpl   = (unsigned short*)(W + OFF_HPL);
    unsigned short* fw2h  = (unsigned short*)(W + OFF_FW2H);
    unsigned short* fw2l  = (unsigned short*)(W + OFF_FW2L);
    unsigned short* kwth  = (unsigned short*)(W + OFF_KWTH);
    unsigned short* kwtl  = (unsigned short*)(W + OFF_KWTL);
    unsigned short* m2th  = (unsigned short*)(W + OFF_M2);
    unsigned short* m2tl  = (unsigned short*)(W + OFF_M2 + 524288ull);
    float*          m2p   = (float*)(W + OFF_M2P);
    float*          pkp   = (float*)(W + OFF_PKP);
    float*          b2    = (float*)(W + OFF_B2);
    unsigned short* featsb= (unsigned short*)(W + OFF_FEATS);
    float*          pkbuf = (float*)(W + OFF_PK);
    unsigned short* h1    = (unsigned short*)(W + OFF_H1);
    unsigned short* h2    = (unsigned short*)(W + OFF_H2);
    float*          pf    = (float*)(W + OFF_PF);
    unsigned short* ew1t  = (unsigned short*)(W + OFF_EW1T);
    unsigned short* ew2t  = (unsigned short*)(W + OFF_EW2T);
    unsigned short* ew3t  = (unsigned short*)(W + OFF_EW3T);
    float*          wslot = (float*)(W + OFF_WSL);
    int*            rowsl = (int*)(W + OFF_RSL);
    int*            sl    = (int*)(W + OFF_SL);
    int*            top_e = (int*)(W + OFF_TOPE);
    float*          top_w = (float*)(W + OFF_TOPW);
    int*            cnt   = (int*)(W + OFF_CNT);
    int*            cnt2  = cnt + 8;
    int*            offs  = cnt + 16;

    float* outF = (float*)d_out;
    float* outW = outF + 8192000;
    float* outT = outF + 8257536;
    float* outS = outF + 8273920;

    // outF/outT/outS are fully written by k_combine/k_route; only outW is scattered.
    hipMemsetAsync(outW, 0, 65536 * sizeof(float), stream);
    hipMemsetAsync(W + OFF_CNT, 0, 256, stream);

    // conversions / transposes (ws is re-poisoned every call; must redo each launch)
    k_split_convert<<<dim3((BB * DD) / 1024), 256, 0, stream>>>(x, x_hi, x_lo, BB * DD);
    k_split_convert<<<dim3((HH * HH) / 1024), 256, 0, stream>>>(fw2, fw2h, fw2l, HH * HH);
    k_transpose<true ><<<dim3(128 / 32, HH / 32, 1), 256, 0, stream>>>(kw, kwth, kwtl, HH, 128, 128);
    k_transpose<true ><<<dim3(HH / 32, DD / 32, 1), 256, 0, stream>>>(fw1, w1th, w1tl, DD, HH, HH);
    k_transpose<false><<<dim3(HH / 32, HH / 32, 1), 256, 0, stream>>>(fw2, w2t, nullptr, HH, HH, HH);
    k_transpose<false><<<dim3(HH / 32, HH / 32, EE), 256, 0, stream>>>(ew1, ew1t, nullptr, HH, HH, HH);
    k_transpose<false><<<dim3(HM / 32, HH / 32, EE), 256, 0, stream>>>(ew2, ew2t, nullptr, HH, HM, HM);
    k_transpose<false><<<dim3(CP / 32, HM / 32, EE), 256, 0, stream>>>(ew3, ew3t, nullptr, HM, CC, CP);

    // M2 = fw2 @ kw  (3-term split MFMA, split-K=8, then reduce+transpose+split)
    k_split3<<<dim3(HH / 128, 8), 256, 0, stream>>>(fw2h, fw2l, kwth, kwtl, m2p, HH, HH / 8);
    k_m2red<<<dim3(HH / 32, 128 / 32), 256, 0, stream>>>(m2p, m2th, m2tl);
    k_bias2<<<dim3(128), 64, 0, stream>>>(fb2, kw, kb, b2);

    // features
    k_l1<<<dim3(BB / 128, HH / 128), 256, 0, stream>>>(x_hi, x_lo, w1th, w1tl, fb1, hph, hpl);
    k_l2<<<dim3(BB / 256, HH / 256), 512, 0, stream>>>(hph, w2t, fb2, featsb);

    // pk = hpre @ M2 (3-term split MFMA, split-K=4, then reduce + bias)
    k_split3<<<dim3(BB / 128, 4), 256, 0, stream>>>(hph, hpl, m2th, m2tl, pkp, HH, HH / 4);
    k_pkred<<<dim3((BB * 128) / 256), 256, 0, stream>>>(pkp, b2, pkbuf);

    // routing
    k_route<<<dim3(BB), 64, 0, stream>>>(pkbuf, keys, outW, outT, outS, top_e, top_w, cnt);
    // pkbuf is dead now; zero the slot arrays that alias it (pad slots -> b=0, w=0)
    hipMemsetAsync(W + OFF_WSL, 0, 147456, stream);
    k_offs<<<1, 1, 0, stream>>>(cnt, offs);
    k_scatter<<<dim3(BB / 256), 256, 0, stream>>>(top_e, top_w, offs, cnt2, rowsl, wslot, sl);

    // experts (top-2 only); L1 gathers feats rows in-GEMM via rowslot
    k_le<true , 4><<<dim3(NT2, HH / 256), 512, 0, stream>>>(featsb, ew1t, eb1, h1, offs, rowsl, HH, HH);
    k_le<false, 2><<<dim3(NT2, HM / 128), 512, 0, stream>>>(h1, ew2t, eb2, h2, offs, nullptr, HM, HH);
    // final: weighted per-slot partial (pf aliases h1, dead after expert L2), then combine
    k_final<<<dim3(NT2, CP / 128), 512, 0, stream>>>(h2, ew3t, eb3, pf, offs, wslot);
    k_combine<<<dim3(BB), 256, 0, stream>>>(pf, sl, outF);
}

// Round 9
// 1298.087 us; speedup vs baseline: 2.2478x; 1.0109x over previous
//
#include <hip/hip_runtime.h>

// ---------- types / helpers ----------
typedef __attribute__((ext_vector_type(8))) short short8;   // 8 x bf16 bits
typedef __attribute__((ext_vector_type(4))) float float4v;
typedef __attribute__((ext_vector_type(4))) unsigned short u16x4;

__device__ __forceinline__ float bf2f(unsigned short u) {
    union { unsigned int i; float f; } v; v.i = ((unsigned int)u) << 16; return v.f;
}
__device__ __forceinline__ unsigned short f2bf(float f) {   // round-to-nearest-even
    union { float f; unsigned int u; } v; v.f = f;
    unsigned int u = v.u;
    return (unsigned short)((u + 0x7fffu + ((u >> 16) & 1u)) >> 16);
}
__device__ __forceinline__ void load_lds16(const void* g, void* l) {
    __builtin_amdgcn_global_load_lds((const __attribute__((address_space(1))) void*)g,
                                     (__attribute__((address_space(3))) void*)l, 16, 0, 0);
}
__device__ __forceinline__ float wred(float v) {
#pragma unroll
    for (int o = 32; o > 0; o >>= 1) v += __shfl_down(v, o);
    return __shfl(v, 0);
}

// ---------- problem dims ----------
#define BB 8192
#define DD 1024
#define HH 2048
#define HM 1024
#define CC 1000
#define CP 1024
#define EE 8
#define CAP2 18432          // 72 row tiles of 256 (expert capacity, 256-padded)
#define NT2 72

// ---------- ws layout (bytes) ----------
#define OFF_XHI   0ull
#define OFF_XLO   16777216ull
#define OFF_W1TH  33554432ull
#define OFF_W1TL  37748736ull
#define OFF_W2T   41943040ull
#define OFF_HPH   50331648ull   // ends 83886080
#define OFF_HPL   83886080ull   // ends 117440512
#define OFF_M2    117440512ull  // m2th (0.5MB) + m2tl (0.5MB)
#define OFF_B2    118489088ull
#define OFF_FEATS 118490112ull  // bf16 feats, ends 152044544 (LIVE through expert L1)
#define OFF_PK    152044544ull  // ends 156238848 (kwt hi/lo early, pkbuf mid, slots late)
#define OFF_H1    0ull          // alias: x/w1t/w2t/hph region — dead after pk split3; 75.5MB
#define OFF_EW1T  156238848ull  // ends 223347712
#define OFF_H2    156238848ull  // alias ew1T (dead after expert L1); 37.7MB
#define OFF_EW2T  223347712ull
#define OFF_EW3T  256902144ull
#define OFF_TOPE  273818624ull
#define OFF_TOPW  273884160ull
#define OFF_CNT   273949696ull
// aliases
#define OFF_FW2H  OFF_HPH                  // 8.4MB, dead before l1 writes hph
#define OFF_FW2L  (OFF_HPH + 8388608ull)
#define OFF_KWTH  OFF_PK                   // 0.5MB, dead before pkred writes pkbuf
#define OFF_KWTL  (OFF_PK + 524288ull)
#define OFF_M2P   OFF_FEATS                // 8MB partials, dead before l2 writes feats
#define OFF_PKP   0ull                     // 16.8MB partials, dead before h1 written
#define OFF_WSL   OFF_PK                   // wslot[18432] f32 — pkbuf dead after k_route
#define OFF_RSL   (OFF_PK + 73728ull)      // rowslot[18432] i32
#define OFF_SL    (OFF_PK + 147456ull)     // sl[16384] i32: b -> its two slots
#define OFF_PF    0ull                     // pf[CAP2][CP] f32 (75.5MB) — aliases h1 (dead after expert L2)

// ---------- XCD-chunked grid swizzle ----------
#define SWZ_G 4
__device__ __forceinline__ void remap_xy(int& x, int& y) {
    const int nbx = gridDim.x, nby = gridDim.y;
    int lin = blockIdx.y * nbx + blockIdx.x;
    int xcd = lin & 7, idx = lin >> 3;
    int rpx = nbx >> 3;                 // row-tiles per xcd
    int gs  = rpx * SWZ_G;              // blocks per col-group within chunk
    int grp = idx / gs, wi = idx - grp * gs;
    int xl  = wi / SWZ_G, yl = wi - xl * SWZ_G;
    x = xcd * rpx + xl;
    y = grp * SWZ_G + yl;
}

// ---------- conversion kernels ----------
__global__ __launch_bounds__(256) void k_split_convert(const float* __restrict__ in,
    unsigned short* __restrict__ hi, unsigned short* __restrict__ lo, int n)
{
    int i = (blockIdx.x * 256 + threadIdx.x) * 4;
    if (i >= n) return;
    float4 v = *(const float4*)(in + i);
    unsigned short h0 = f2bf(v.x), h1 = f2bf(v.y), h2 = f2bf(v.z), h3 = f2bf(v.w);
    u16x4 hv = {h0, h1, h2, h3};
    u16x4 lv = {f2bf(v.x - bf2f(h0)), f2bf(v.y - bf2f(h1)),
                f2bf(v.z - bf2f(h2)), f2bf(v.w - bf2f(h3))};
    *(u16x4*)(hi + i) = hv;
    *(u16x4*)(lo + i) = lv;
}

// out[b][n][k] = in[b][k][n]  (bf16, zero-pad n >= N up to Npad)
template<bool SPLIT>
__global__ __launch_bounds__(256) void k_transpose(const float* __restrict__ in,
    unsigned short* __restrict__ hi, unsigned short* __restrict__ lo, int K, int N, int Npad)
{
    __shared__ float tile[32][33];
    const float* src = in + (size_t)blockIdx.z * K * N;
    int n0 = blockIdx.x * 32, k0 = blockIdx.y * 32;
    int tx = threadIdx.x & 31, ty = threadIdx.x >> 5;
#pragma unroll
    for (int r = ty; r < 32; r += 8) {
        int n = n0 + tx;
        tile[r][tx] = (n < N) ? src[(size_t)(k0 + r) * N + n] : 0.f;
    }
    __syncthreads();
    size_t ob = (size_t)blockIdx.z * Npad * K;
    {
        int n  = threadIdx.x >> 3;          // 0..31  (output row within tile)
        int kq = (threadIdx.x & 7) * 4;     // 0..28  (output col quad, contiguous in K)
        u16x4 hv, lv;
#pragma unroll
        for (int i = 0; i < 4; ++i) {
            float v = tile[kq + i][n];
            unsigned short h = f2bf(v);
            hv[i] = h;
            lv[i] = SPLIT ? f2bf(v - bf2f(h)) : (unsigned short)0;
        }
        size_t o = ob + (size_t)(n0 + n) * K + k0 + kq;
        *(u16x4*)(hi + o) = hv;
        if (SPLIT) *(u16x4*)(lo + o) = lv;
    }
}

// ============================================================================
// BK=64 4-phase core (kept for k_l2 only: grid=256 is perfectly packed at 1/CU)
// ============================================================================
template<int NB>
__device__ __forceinline__ void gemm256(
    const unsigned short* __restrict__ a0, const unsigned short* __restrict__ a1,
    const unsigned short* __restrict__ b0, const unsigned short* __restrict__ b1,
    int K, unsigned short* L, float4v (&acc)[8][NB])
{
    const int tid = threadIdx.x;
    const int lane = tid & 63, w = tid >> 6;
    const int lrow = lane & 15, quad = (lane >> 4) & 3;
    const int wm = w >> 2, wn = w & 3;
    const int NT = K >> 6;
    constexpr int BSH  = NB * 2048;         // B half-tile shorts
    constexpr int BUFS = 16384 + 2 * BSH;   // per-buffer shorts
    constexpr int VM   = (NB == 4) ? 6 : 4; // steady-state vmcnt

    int aoff[8], boff[NB];
#pragma unroll
    for (int i = 0; i < 8; ++i) {
        int r = wm * 128 + i * 16 + lrow;
        aoff[i] = r * 32 + (quad ^ ((r >> 1) & 3)) * 8;
    }
#pragma unroll
    for (int j = 0; j < NB; ++j) {
        int r = wn * (NB * 16) + j * 16 + lrow;
        boff[j] = r * 32 + (quad ^ ((r >> 1) & 3)) * 8;
    }
    unsigned short* const dA = L + w * 512;
    unsigned short* const dB = L + 16384 + w * 512;

    auto stgA = [&](int t, int kh, int buf) {
        unsigned short* d = dA + buf * BUFS + kh * 8192;
        const int ko = t * 64 + kh * 32;
        load_lds16(a0 + ko, d);
        load_lds16(a1 + ko, d + 4096);
    };
    auto stgB = [&](int t, int kh, int buf) {
        unsigned short* d = dB + buf * BUFS + kh * BSH;
        const int ko = t * 64 + kh * 32;
        load_lds16(b0 + ko, d);
        if constexpr (NB == 4) load_lds16(b1 + ko, d + 4096);
    };

    stgA(0, 0, 0); stgA(0, 1, 0); stgB(0, 0, 0); stgB(0, 1, 0);
    if (NT > 1) { stgB(1, 0, 1); stgA(1, 0, 1); stgB(1, 1, 1); }
    asm volatile("s_waitcnt vmcnt(%0)" :: "i"(VM) : "memory");
    __builtin_amdgcn_s_barrier();

    short8 af[4], bfr[NB];
    for (int t = 0; t < NT; ++t) {
        const int buf = t & 1;
        const unsigned short* Lb = L + buf * BUFS;
        // ---- P1: M-lo, k0 ----
#pragma unroll
        for (int i = 0; i < 4; ++i) af[i]  = *(const short8*)(Lb + aoff[i]);
#pragma unroll
        for (int j = 0; j < NB; ++j) bfr[j] = *(const short8*)(Lb + 16384 + boff[j]);
        if (t + 1 < NT) stgA(t + 1, 1, buf ^ 1);
        __builtin_amdgcn_s_barrier();
        __builtin_amdgcn_s_setprio(1);
#pragma unroll
        for (int i = 0; i < 4; ++i)
#pragma unroll
            for (int j = 0; j < NB; ++j)
                acc[i][j] = __builtin_amdgcn_mfma_f32_16x16x32_bf16(af[i], bfr[j], acc[i][j], 0, 0, 0);
        __builtin_amdgcn_s_setprio(0);
        __builtin_amdgcn_s_barrier();
        // ---- P2: M-hi, k0 ----
#pragma unroll
        for (int i = 0; i < 4; ++i) af[i] = *(const short8*)(Lb + aoff[4 + i]);
        if (t + 2 < NT) stgB(t + 2, 0, buf);
        __builtin_amdgcn_s_barrier();
        __builtin_amdgcn_s_setprio(1);
#pragma unroll
        for (int i = 0; i < 4; ++i)
#pragma unroll
            for (int j = 0; j < NB; ++j)
                acc[4 + i][j] = __builtin_amdgcn_mfma_f32_16x16x32_bf16(af[i], bfr[j], acc[4 + i][j], 0, 0, 0);
        __builtin_amdgcn_s_setprio(0);
        __builtin_amdgcn_s_barrier();
        // ---- P3: M-lo, k1 ----
#pragma unroll
        for (int i = 0; i < 4; ++i) af[i]  = *(const short8*)(Lb + 8192 + aoff[i]);
#pragma unroll
        for (int j = 0; j < NB; ++j) bfr[j] = *(const short8*)(Lb + 16384 + BSH + boff[j]);
        if (t + 2 < NT) stgA(t + 2, 0, buf);
        __builtin_amdgcn_s_barrier();
        __builtin_amdgcn_s_setprio(1);
#pragma unroll
        for (int i = 0; i < 4; ++i)
#pragma unroll
            for (int j = 0; j < NB; ++j)
                acc[i][j] = __builtin_amdgcn_mfma_f32_16x16x32_bf16(af[i], bfr[j], acc[i][j], 0, 0, 0);
        __builtin_amdgcn_s_setprio(0);
        __builtin_amdgcn_s_barrier();
        // ---- P4: M-hi, k1 ----
#pragma unroll
        for (int i = 0; i < 4; ++i) af[i] = *(const short8*)(Lb + 8192 + aoff[4 + i]);
        if (t + 2 < NT) {
            stgB(t + 2, 1, buf);
            asm volatile("s_waitcnt vmcnt(%0)" :: "i"(VM) : "memory");
        } else {
            asm volatile("s_waitcnt vmcnt(0)" ::: "memory");
        }
        __builtin_amdgcn_s_barrier();
        __builtin_amdgcn_s_setprio(1);
#pragma unroll
        for (int i = 0; i < 4; ++i)
#pragma unroll
            for (int j = 0; j < NB; ++j)
                acc[4 + i][j] = __builtin_amdgcn_mfma_f32_16x16x32_bf16(af[i], bfr[j], acc[4 + i][j], 0, 0, 0);
        __builtin_amdgcn_s_setprio(0);
        __builtin_amdgcn_s_barrier();
    }
}

// ============================================================================
// BK=32 TRIPLE-buffered core with counted vmcnt (R9). 512 thr = 8 waves (2Mx4N).
// LDS: 3 buf x (A 8192 + B NB*2048 shorts) = 96KB (NB=4) / 72KB (NB=2).
// Schedule per tile t: stage tile t+2 -> r2 (issue-early), P1 Mlo MFMA, P2 Mhi
// MFMA, then vmcnt(SL) — waits ONLY tile t+1's SL loads, which have been in
// flight ~2 full tiles (~2500cy >> 900cy HBM latency, m126) -> drain is free in
// steady state. R5/R8's vmcnt(0)-per-tile had a ~1-tile window < HBM latency:
// every tile stalled in the drain (R5 208us ~= R8 204us at both 1 and 2 blk/CU
// disproved occupancy as the lever; barrier-count 256 vs 64 also ~equal).
// Hazards: stage target r2 = buffer read at tile t-1, whose ds_reads completed
// before the end-of-(t-1) barrier that precedes this stage (sched_barrier(0)
// pins issue order; raw s_barrier is not a compiler fence — rule #18).
// Tail: t+2>=NT -> vmcnt(0). launch_bounds (512,2): arg=4 capped VGPR at 64 and
// spilled (R7: WRITE 3.97GB); arg=2 -> cap 128, VGPR ~92, no spill.
// ============================================================================
template<int NB>
__device__ __forceinline__ void gemm256b(
    const unsigned short* __restrict__ a0, const unsigned short* __restrict__ a1,
    const unsigned short* __restrict__ b0, const unsigned short* __restrict__ b1,
    int K, unsigned short* L, float4v (&acc)[8][NB])
{
    const int tid = threadIdx.x;
    const int lane = tid & 63, w = tid >> 6;
    const int lrow = lane & 15, quad = (lane >> 4) & 3;
    const int wm = w >> 2, wn = w & 3;
    const int NT = K >> 5;
    constexpr int BUFS = 8192 + NB * 2048;  // per-buffer shorts
    constexpr int SL   = (NB == 4) ? 4 : 3; // loads per stage

    int aoff[8], boff[NB];
#pragma unroll
    for (int i = 0; i < 8; ++i) {
        int r = wm * 128 + i * 16 + lrow;
        aoff[i] = r * 32 + (quad ^ ((r >> 1) & 3)) * 8;
    }
#pragma unroll
    for (int j = 0; j < NB; ++j) {
        int r = wn * (NB * 16) + j * 16 + lrow;
        boff[j] = r * 32 + (quad ^ ((r >> 1) & 3)) * 8;
    }
    const int dAo = w * 512;            // wave-uniform LDS dest offsets
    const int dBo = 8192 + w * 512;

    auto stg = [&](int t, unsigned short* buf) {   // stage full K-tile t into buf
        const int ko = t * 32;
        load_lds16(a0 + ko, buf + dAo);            // M-lo rows
        load_lds16(a1 + ko, buf + dAo + 4096);     // M-hi rows
        load_lds16(b0 + ko, buf + dBo);
        if constexpr (NB == 4) load_lds16(b1 + ko, buf + dBo + 4096);
    };

    unsigned short* r0 = L;              // tile t   (read)
    unsigned short* r1 = L + BUFS;       // tile t+1 (in flight)
    unsigned short* r2 = L + 2 * BUFS;   // tile t+2 (stage target)

    // prologue: tiles 0,1 in flight; wait tile 0 only (vmcnt(SL) retires oldest SL)
    stg(0, r0);
    if (NT > 1) {
        stg(1, r1);
        asm volatile("s_waitcnt vmcnt(%0)" :: "i"(SL) : "memory");
    } else {
        asm volatile("s_waitcnt vmcnt(0)" ::: "memory");
    }
    __builtin_amdgcn_sched_barrier(0);
    __builtin_amdgcn_s_barrier();
    __builtin_amdgcn_sched_barrier(0);

    short8 af[4], bfr[NB];
    for (int t = 0; t < NT; ++t) {
        if (t + 2 < NT) stg(t + 2, r2);     // issue-early: 2-tile flight window
        // ---- P1: M-lo ----
#pragma unroll
        for (int i = 0; i < 4; ++i) af[i]  = *(const short8*)(r0 + aoff[i]);
#pragma unroll
        for (int j = 0; j < NB; ++j) bfr[j] = *(const short8*)(r0 + 8192 + boff[j]);
        __builtin_amdgcn_s_setprio(1);
#pragma unroll
        for (int i = 0; i < 4; ++i)
#pragma unroll
            for (int j = 0; j < NB; ++j)
                acc[i][j] = __builtin_amdgcn_mfma_f32_16x16x32_bf16(af[i], bfr[j], acc[i][j], 0, 0, 0);
        __builtin_amdgcn_s_setprio(0);
        // ---- P2: M-hi (reuse bfr) ----
#pragma unroll
        for (int i = 0; i < 4; ++i) af[i] = *(const short8*)(r0 + aoff[4 + i]);
        __builtin_amdgcn_s_setprio(1);
#pragma unroll
        for (int i = 0; i < 4; ++i)
#pragma unroll
            for (int j = 0; j < NB; ++j)
                acc[4 + i][j] = __builtin_amdgcn_mfma_f32_16x16x32_bf16(af[i], bfr[j], acc[4 + i][j], 0, 0, 0);
        __builtin_amdgcn_s_setprio(0);
        // drain: wait tile t+1 only (counted); full drain in 2-tile tail
        if (t + 2 < NT)
            asm volatile("s_waitcnt vmcnt(%0)" :: "i"(SL) : "memory");
        else
            asm volatile("s_waitcnt vmcnt(0)" ::: "memory");
        __builtin_amdgcn_sched_barrier(0);
        __builtin_amdgcn_s_barrier();
        __builtin_amdgcn_sched_barrier(0);
        unsigned short* tmp = r0; r0 = r1; r1 = r2; r2 = tmp;   // rotate
    }
}

// ---------- layer 1: split (bf16x2) GEMM, relu, split-store (128^2 structure) ----------
__global__ __launch_bounds__(256, 2) void k_l1(
    const unsigned short* __restrict__ xh, const unsigned short* __restrict__ xl,
    const unsigned short* __restrict__ wh, const unsigned short* __restrict__ wl,
    const float* __restrict__ bias, unsigned short* __restrict__ oh, unsigned short* __restrict__ ol)
{
    __shared__ __align__(16) unsigned short Ash[4096], Asl[4096], Bsh[4096], Bsl[4096];
    const int K = DD, N = HH;
    int bx, by; remap_xy(bx, by);
    const int row0 = bx * 128, col0 = by * 128;
    const int t = threadIdx.x, lane = t & 63, w = t >> 6;
    const int lrow = lane & 15, quad = lane >> 4;
    const int swz = (quad ^ ((lrow >> 1) & 3)) * 8;
    const int wr = (w & 1) * 64, wc = (w >> 1) * 64;
    float4v acc[4][4] = {};
    for (int k0 = 0; k0 < K; k0 += 32) {
#pragma unroll
        for (int p = 0; p < 2; ++p) {
            int c = p * 256 + t;
            int r = c >> 2, q = (c & 3) ^ ((r >> 1) & 3);
            size_t ga = (size_t)(row0 + r) * K + k0 + q * 8;
            size_t gb = (size_t)(col0 + r) * K + k0 + q * 8;
            int lo_ = (p * 256 + w * 64) * 8;
            load_lds16(xh + ga, Ash + lo_);
            load_lds16(xl + ga, Asl + lo_);
            load_lds16(wh + gb, Bsh + lo_);
            load_lds16(wl + gb, Bsl + lo_);
        }
        __syncthreads();
        short8 ah[4], al[4], bh[4], bl[4];
#pragma unroll
        for (int i = 0; i < 4; ++i) {
            int o = (wr + i * 16 + lrow) * 32 + swz;
            ah[i] = *(const short8*)(Ash + o);
            al[i] = *(const short8*)(Asl + o);
        }
#pragma unroll
        for (int j = 0; j < 4; ++j) {
            int o = (wc + j * 16 + lrow) * 32 + swz;
            bh[j] = *(const short8*)(Bsh + o);
            bl[j] = *(const short8*)(Bsl + o);
        }
#pragma unroll
        for (int i = 0; i < 4; ++i)
#pragma unroll
            for (int j = 0; j < 4; ++j) {
                float4v a0 = __builtin_amdgcn_mfma_f32_16x16x32_bf16(al[i], bh[j], acc[i][j], 0, 0, 0);
                a0 = __builtin_amdgcn_mfma_f32_16x16x32_bf16(ah[i], bl[j], a0, 0, 0, 0);
                acc[i][j] = __builtin_amdgcn_mfma_f32_16x16x32_bf16(ah[i], bh[j], a0, 0, 0, 0);
            }
        __syncthreads();
    }
#pragma unroll
    for (int i = 0; i < 4; ++i)
#pragma unroll
        for (int r = 0; r < 4; ++r) {
            int row = row0 + wr + i * 16 + quad * 4 + r;
            size_t base = (size_t)row * N;
#pragma unroll
            for (int j = 0; j < 4; ++j) {
                int col = col0 + wc + j * 16 + lrow;
                float v = fmaxf(acc[i][j][r] + bias[col], 0.f);
                unsigned short h = f2bf(v);
                oh[base + col] = h;
                ol[base + col] = f2bf(v - bf2f(h));
            }
        }
}

// ---------- generic 3-term split GEMM, N=128, split-K, fp32 partial out ----------
__global__ __launch_bounds__(256, 2) void k_split3(
    const unsigned short* __restrict__ ah_, const unsigned short* __restrict__ al_,
    const unsigned short* __restrict__ bh_, const unsigned short* __restrict__ bl_,
    float* __restrict__ out, int K, int klen)
{
    __shared__ __align__(16) unsigned short Ash[4096], Asl[4096], Bsh[4096], Bsl[4096];
    const int row0 = blockIdx.x * 128;
    const int kb = blockIdx.y * klen;
    out += (size_t)blockIdx.y * gridDim.x * 128 * 128;
    const int t = threadIdx.x, lane = t & 63, w = t >> 6;
    const int lrow = lane & 15, quad = lane >> 4;
    const int swz = (quad ^ ((lrow >> 1) & 3)) * 8;
    const int wr = (w & 1) * 64, wc = (w >> 1) * 64;
    float4v acc[4][4] = {};
    for (int k0 = kb; k0 < kb + klen; k0 += 32) {
#pragma unroll
        for (int p = 0; p < 2; ++p) {
            int c = p * 256 + t;
            int r = c >> 2, q = (c & 3) ^ ((r >> 1) & 3);
            size_t ga = (size_t)(row0 + r) * K + k0 + q * 8;
            size_t gb = (size_t)r * K + k0 + q * 8;           // B has exactly 128 rows
            int lo_ = (p * 256 + w * 64) * 8;
            load_lds16(ah_ + ga, Ash + lo_);
            load_lds16(al_ + ga, Asl + lo_);
            load_lds16(bh_ + gb, Bsh + lo_);
            load_lds16(bl_ + gb, Bsl + lo_);
        }
        __syncthreads();
        short8 ah[4], al[4], bh[4], bl[4];
#pragma unroll
        for (int i = 0; i < 4; ++i) {
            int o = (wr + i * 16 + lrow) * 32 + swz;
            ah[i] = *(const short8*)(Ash + o);
            al[i] = *(const short8*)(Asl + o);
        }
#pragma unroll
        for (int j = 0; j < 4; ++j) {
            int o = (wc + j * 16 + lrow) * 32 + swz;
            bh[j] = *(const short8*)(Bsh + o);
            bl[j] = *(const short8*)(Bsl + o);
        }
#pragma unroll
        for (int i = 0; i < 4; ++i)
#pragma unroll
            for (int j = 0; j < 4; ++j) {
                float4v a0 = __builtin_amdgcn_mfma_f32_16x16x32_bf16(al[i], bh[j], acc[i][j], 0, 0, 0);
                a0 = __builtin_amdgcn_mfma_f32_16x16x32_bf16(ah[i], bl[j], a0, 0, 0, 0);
                acc[i][j] = __builtin_amdgcn_mfma_f32_16x16x32_bf16(ah[i], bh[j], a0, 0, 0, 0);
            }
        __syncthreads();
    }
#pragma unroll
    for (int i = 0; i < 4; ++i)
#pragma unroll
        for (int r = 0; r < 4; ++r) {
            int row = row0 + wr + i * 16 + quad * 4 + r;
            size_t base = (size_t)row * 128;
#pragma unroll
            for (int j = 0; j < 4; ++j) {
                int col = wc + j * 16 + lrow;
                out[base + col] = acc[i][j][r];
            }
        }
}

// ---------- M2 reduce: sum 8 partials, transpose, split to bf16 hi/lo ----------
__global__ __launch_bounds__(256) void k_m2red(const float* __restrict__ p,
    unsigned short* __restrict__ th, unsigned short* __restrict__ tl)
{
    __shared__ float tile[32][33];
    const int h0 = blockIdx.x * 32, c0 = blockIdx.y * 32;
    const int t = threadIdx.x;
    {
        int r = t >> 3, cq = (t & 7) * 4;
        size_t base = (size_t)(h0 + r) * 128 + c0 + cq;
        float4 s = *(const float4*)(p + base);
#pragma unroll
        for (int ks = 1; ks < 8; ++ks) {
            float4 v = *(const float4*)(p + (size_t)ks * HH * 128 + base);
            s.x += v.x; s.y += v.y; s.z += v.z; s.w += v.w;
        }
        tile[r][cq] = s.x; tile[r][cq + 1] = s.y; tile[r][cq + 2] = s.z; tile[r][cq + 3] = s.w;
    }
    __syncthreads();
    {
        int cr = t >> 3, hq = (t & 7) * 4;
        u16x4 hv, lv;
#pragma unroll
        for (int i = 0; i < 4; ++i) {
            float v = tile[hq + i][cr];
            unsigned short h = f2bf(v);
            hv[i] = h; lv[i] = f2bf(v - bf2f(h));
        }
        size_t o = (size_t)(c0 + cr) * HH + h0 + hq;
        *(u16x4*)(th + o) = hv;
        *(u16x4*)(tl + o) = lv;
    }
}

// ---------- pk reduce: sum 4 partials + bias ----------
__global__ __launch_bounds__(256) void k_pkred(const float* __restrict__ p,
    const float* __restrict__ b2, float* __restrict__ out)
{
    int idx = blockIdx.x * 256 + threadIdx.x;
    const size_t S = (size_t)BB * 128;
    out[idx] = p[idx] + p[idx + S] + p[idx + 2 * S] + p[idx + 3 * S] + b2[idx & 127];
}

// ---------- layer 2: single bf16 GEMM -> feats bf16 (no relu), 256^2 BK=64 ----------
__global__ __launch_bounds__(512, 2) void k_l2(const unsigned short* __restrict__ A,
    const unsigned short* __restrict__ Bt, const float* __restrict__ bias,
    unsigned short* __restrict__ outb)
{
    __shared__ __align__(16) unsigned short L[65536];
    const int K = HH, N = HH;
    int bx, by; remap_xy(bx, by);
    const int row0 = bx * 256, col0 = by * 256;
    const int tid = threadIdx.x;
    const int r0 = tid >> 2, c0 = tid & 3;
    const int csw = (c0 ^ ((r0 >> 1) & 3)) * 8;
    const unsigned short* a0 = A + (size_t)(row0 + r0) * K + csw;
    const unsigned short* a1 = a0 + (size_t)128 * K;
    const unsigned short* b0 = Bt + (size_t)(col0 + r0) * K + csw;
    const unsigned short* b1 = b0 + (size_t)128 * K;
    float4v acc[8][4] = {};
    gemm256<4>(a0, a1, b0, b1, K, L, acc);
    const int lane = tid & 63, w = tid >> 6;
    const int lrow = lane & 15, quad = (lane >> 4) & 3;
    const int wm = w >> 2, wn = w & 3;
#pragma unroll
    for (int ii = 0; ii < 8; ++ii)
#pragma unroll
        for (int rr = 0; rr < 4; ++rr) {
            int row = row0 + wm * 128 + ii * 16 + quad * 4 + rr;
            size_t base = (size_t)row * N;
#pragma unroll
            for (int j = 0; j < 4; ++j) {
                int col = col0 + wn * 64 + j * 16 + lrow;
                outb[base + col] = f2bf(acc[ii][j][rr] + bias[col]);
            }
        }
}

// ---------- expert GEMM (relu, bf16 out), 256xBN BK=32 3-buf; IND: rows via rowslot ----------
template<bool IND, int NB>
__global__ __launch_bounds__(512, 2) void k_le(const unsigned short* __restrict__ A,
    const unsigned short* __restrict__ WT, const float* __restrict__ bias,
    unsigned short* __restrict__ out, const int* __restrict__ offs,
    const int* __restrict__ rowslot, int N, int K)
{
    __shared__ __align__(16) unsigned short L[3 * (8192 + NB * 2048)];
    int bx, by; remap_xy(bx, by);
    const int row0 = bx * 256;
    if (row0 >= offs[8]) return;
    int e = 0;
#pragma unroll
    for (int i = 1; i < 8; ++i) if (offs[i] <= row0) e = i;
    const unsigned short* Bt = WT + (size_t)e * N * K;
    const float* bs = bias + (size_t)e * N;
    const int col0 = by * (NB * 64);
    const int tid = threadIdx.x;
    const int r0 = tid >> 2, c0 = tid & 3;
    const int csw = (c0 ^ ((r0 >> 1) & 3)) * 8;
    const int gr0 = IND ? rowslot[row0 + r0] : (row0 + r0);
    const int gr1 = IND ? rowslot[row0 + 128 + r0] : (row0 + 128 + r0);
    const unsigned short* a0 = A + (size_t)gr0 * K + csw;
    const unsigned short* a1 = A + (size_t)gr1 * K + csw;
    const unsigned short* b0 = Bt + (size_t)(col0 + r0) * K + csw;
    const unsigned short* b1 = b0 + (size_t)128 * K;
    float4v acc[8][NB] = {};
    gemm256b<NB>(a0, a1, b0, b1, K, L, acc);
    const int lane = tid & 63, w = tid >> 6;
    const int lrow = lane & 15, quad = (lane >> 4) & 3;
    const int wm = w >> 2, wn = w & 3;
#pragma unroll
    for (int ii = 0; ii < 8; ++ii)
#pragma unroll
        for (int rr = 0; rr < 4; ++rr) {
            int row = row0 + wm * 128 + ii * 16 + quad * 4 + rr;
            size_t base = (size_t)row * N;
#pragma unroll
            for (int j = 0; j < NB; ++j) {
                int col = col0 + wn * (NB * 16) + j * 16 + lrow;
                out[base + col] = f2bf(fmaxf(acc[ii][j][rr] + bs[col], 0.f));
            }
        }
}

// ---------- final expert GEMM: weighted per-slot partial (NO atomics), BK=32 3-buf ----------
__global__ __launch_bounds__(512, 2) void k_final(const unsigned short* __restrict__ A,
    const unsigned short* __restrict__ WT, const float* __restrict__ bias,
    float* __restrict__ pf, const int* __restrict__ offs,
    const float* __restrict__ wslot)
{
    constexpr int NB = 2;
    __shared__ __align__(16) unsigned short L[3 * (8192 + NB * 2048)];
    const int N = CP, K = HM;
    int bx, by; remap_xy(bx, by);
    const int row0 = bx * 256;
    if (row0 >= offs[8]) return;
    int e = 0;
#pragma unroll
    for (int i = 1; i < 8; ++i) if (offs[i] <= row0) e = i;
    const unsigned short* Bt = WT + (size_t)e * N * K;
    const float* bs = bias + (size_t)e * CC;
    const int col0 = by * (NB * 64);
    const int tid = threadIdx.x;
    const int r0 = tid >> 2, c0 = tid & 3;
    const int csw = (c0 ^ ((r0 >> 1) & 3)) * 8;
    const unsigned short* a0 = A + (size_t)(row0 + r0) * K + csw;
    const unsigned short* a1 = a0 + (size_t)128 * K;
    const unsigned short* b0 = Bt + (size_t)(col0 + r0) * K + csw;
    float4v acc[8][NB] = {};
    gemm256b<NB>(a0, a1, b0, b0, K, L, acc);
    const int lane = tid & 63, w = tid >> 6;
    const int lrow = lane & 15, quad = (lane >> 4) & 3;
    const int wm = w >> 2, wn = w & 3;
#pragma unroll
    for (int ii = 0; ii < 8; ++ii)
#pragma unroll
        for (int rr = 0; rr < 4; ++rr) {
            int row = row0 + wm * 128 + ii * 16 + quad * 4 + rr;
            float wv = wslot[row];
            if (wv != 0.f) {
                float* prow = pf + (size_t)row * CP;
#pragma unroll
                for (int j = 0; j < NB; ++j) {
                    int col = col0 + wn * (NB * 16) + j * 16 + lrow;
                    if (col < CC) prow[col] = wv * (acc[ii][j][rr] + bs[col]);
                }
            }
        }
}

// ---------- combine: outF[b][c] = pf[sl[2b]][c] + pf[sl[2b+1]][c] ----------
__global__ __launch_bounds__(256) void k_combine(const float* __restrict__ pf,
    const int* __restrict__ sl, float* __restrict__ outF)
{
    int b = blockIdx.x;
    int c = threadIdx.x * 4;
    if (c >= CC) return;
    int s0 = sl[b * 2], s1 = sl[b * 2 + 1];
    float4 v0 = *(const float4*)(pf + (size_t)s0 * CP + c);
    float4 v1 = *(const float4*)(pf + (size_t)s1 * CP + c);
    float4 r; r.x = v0.x + v1.x; r.y = v0.y + v1.y; r.z = v0.z + v1.z; r.w = v0.w + v1.w;
    *(float4*)(outF + (size_t)b * CC + c) = r;
}

// ---------- b2[c] = sum_j fb2[j]*kw[j,c] + kb[c] ----------
__global__ __launch_bounds__(64) void k_bias2(const float* __restrict__ fb2,
    const float* __restrict__ kw, const float* __restrict__ kb, float* __restrict__ b2)
{
    int c = blockIdx.x, lane = threadIdx.x;
    float s = 0.f;
    for (int j = lane; j < HH; j += 64) s += fb2[j] * kw[(size_t)j * 128 + c];
    s = wred(s);
    if (lane == 0) b2[c] = s + kb[c];
}

// ---------- routing ----------
__global__ __launch_bounds__(64) void k_route(const float* __restrict__ pk,
    const float* __restrict__ keys, float* __restrict__ wout, float* __restrict__ tout,
    float* __restrict__ simout, int* __restrict__ top_e, float* __restrict__ top_w,
    int* __restrict__ cnt)
{
    int b = blockIdx.x, lane = threadIdx.x;
    float2 v = *(const float2*)&pk[(size_t)b * 128 + lane * 2];
    float inv = 1.f / fmaxf(sqrtf(wred(v.x * v.x + v.y * v.y)), 1e-12f);
    float sims[8];
#pragma unroll
    for (int e = 0; e < 8; ++e) {
        float2 kv = *(const float2*)&keys[e * 128 + lane * 2];
        float kinv = 1.f / fmaxf(sqrtf(wred(kv.x * kv.x + kv.y * kv.y)), 1e-12f);
        float d = wred(v.x * kv.x + v.y * kv.y);
        sims[e] = d * inv * kinv;
    }
    if (lane == 0) {
        int i1 = 0; float v1 = sims[0];
#pragma unroll
        for (int e = 1; e < 8; ++e) if (sims[e] > v1) { v1 = sims[e]; i1 = e; }
        int i2 = -1; float v2 = -1e30f;
#pragma unroll
        for (int e = 0; e < 8; ++e) if (e != i1 && sims[e] > v2) { v2 = sims[e]; i2 = e; }
        float e2 = expf(v2 - v1);
        float w1 = 1.f / (1.f + e2), w2 = e2 / (1.f + e2);
#pragma unroll
        for (int e = 0; e < 8; ++e) simout[(size_t)b * 8 + e] = sims[e];
        wout[(size_t)b * 8 + i1] = w1;
        wout[(size_t)b * 8 + i2] = w2;
        tout[(size_t)b * 2] = (float)i1; tout[(size_t)b * 2 + 1] = (float)i2;
        top_e[b * 2] = i1; top_e[b * 2 + 1] = i2;
        top_w[b * 2] = w1; top_w[b * 2 + 1] = w2;
        atomicAdd(&cnt[i1], 1); atomicAdd(&cnt[i2], 1);
    }
}

__global__ void k_offs(const int* __restrict__ cnt, int* __restrict__ offs)
{
    if (threadIdx.x == 0) {
        int o = 0;
        for (int e = 0; e < 8; ++e) { offs[e] = o; o += ((cnt[e] + 255) >> 8) << 8; }
        offs[8] = o;
    }
}

__global__ __launch_bounds__(256) void k_scatter(const int* __restrict__ top_e,
    const float* __restrict__ top_w, const int* __restrict__ offs, int* __restrict__ cnt2,
    int* __restrict__ rowslot, float* __restrict__ wslot, int* __restrict__ sl)
{
    int b = blockIdx.x * 256 + threadIdx.x;
    if (b >= BB) return;
#pragma unroll
    for (int j = 0; j < 2; ++j) {
        int e = top_e[b * 2 + j];
        int idx = atomicAdd(&cnt2[e], 1);
        int s = offs[e] + idx;
        rowslot[s] = b;
        wslot[s] = top_w[b * 2 + j];
        sl[b * 2 + j] = s;
    }
}

// ---------- launch ----------
extern "C" void kernel_launch(void* const* d_in, const int* in_sizes, int n_in,
                              void* d_out, int out_size, void* d_ws, size_t ws_size,
                              hipStream_t stream)
{
    const float* x    = (const float*)d_in[0];
    const float* fw1  = (const float*)d_in[1];
    const float* fb1  = (const float*)d_in[2];
    const float* fw2  = (const float*)d_in[3];
    const float* fb2  = (const float*)d_in[4];
    const float* kw   = (const float*)d_in[5];
    const float* kb   = (const float*)d_in[6];
    const float* keys = (const float*)d_in[7];
    const float* ew1  = (const float*)d_in[8];
    const float* eb1  = (const float*)d_in[9];
    const float* ew2  = (const float*)d_in[10];
    const float* eb2  = (const float*)d_in[11];
    const float* ew3  = (const float*)d_in[12];
    const float* eb3  = (const float*)d_in[13];

    char* W = (char*)d_ws;
    unsigned short* x_hi  = (unsigned short*)(W + OFF_XHI);
    unsigned short* x_lo  = (unsigned short*)(W + OFF_XLO);
    unsigned short* w1th  = (unsigned short*)(W + OFF_W1TH);
    unsigned short* w1tl  = (unsigned short*)(W + OFF_W1TL);
    unsigned short* w2t   = (unsigned short*)(W + OFF_W2T);
    unsigned short* hph   = (unsigned short*)(W + OFF_HPH);
    unsigned short* hpl   = (unsigned short*)(W + OFF_HPL);
    unsigned short* fw2h  = (unsigned short*)(W + OFF_FW2H);
    unsigned short* fw2l  = (unsigned short*)(W + OFF_FW2L);
    unsigned short* kwth  = (unsigned short*)(W + OFF_KWTH);
    unsigned short* kwtl  = (unsigned short*)(W + OFF_KWTL);
    unsigned short* m2th  = (unsigned short*)(W + OFF_M2);
    unsigned short* m2tl  = (unsigned short*)(W + OFF_M2 + 524288ull);
    float*          m2p   = (float*)(W + OFF_M2P);
    float*          pkp   = (float*)(W + OFF_PKP);
    float*          b2    = (float*)(W + OFF_B2);
    unsigned short* featsb= (unsigned short*)(W + OFF_FEATS);
    float*          pkbuf = (float*)(W + OFF_PK);
    unsigned short* h1    = (unsigned short*)(W + OFF_H1);
    unsigned short* h2    = (unsigned short*)(W + OFF_H2);
    float*          pf    = (float*)(W + OFF_PF);
    unsigned short* ew1t  = (unsigned short*)(W + OFF_EW1T);
    unsigned short* ew2t  = (unsigned short*)(W + OFF_EW2T);
    unsigned short* ew3t  = (unsigned short*)(W + OFF_EW3T);
    float*          wslot = (float*)(W + OFF_WSL);
    int*            rowsl = (int*)(W + OFF_RSL);
    int*            sl    = (int*)(W + OFF_SL);
    int*            top_e = (int*)(W + OFF_TOPE);
    float*          top_w = (float*)(W + OFF_TOPW);
    int*            cnt   = (int*)(W + OFF_CNT);
    int*            cnt2  = cnt + 8;
    int*            offs  = cnt + 16;

    float* outF = (float*)d_out;
    float* outW = outF + 8192000;
    float* outT = outF + 8257536;
    float* outS = outF + 8273920;

    // outF/outT/outS are fully written by k_combine/k_route; only outW is scattered.
    hipMemsetAsync(outW, 0, 65536 * sizeof(float), stream);
    hipMemsetAsync(W + OFF_CNT, 0, 256, stream);

    // conversions / transposes (ws is re-poisoned every call; must redo each launch)
    k_split_convert<<<dim3((BB * DD) / 1024), 256, 0, stream>>>(x, x_hi, x_lo, BB * DD);
    k_split_convert<<<dim3((HH * HH) / 1024), 256, 0, stream>>>(fw2, fw2h, fw2l, HH * HH);
    k_transpose<true ><<<dim3(128 / 32, HH / 32, 1), 256, 0, stream>>>(kw, kwth, kwtl, HH, 128, 128);
    k_transpose<true ><<<dim3(HH / 32, DD / 32, 1), 256, 0, stream>>>(fw1, w1th, w1tl, DD, HH, HH);
    k_transpose<false><<<dim3(HH / 32, HH / 32, 1), 256, 0, stream>>>(fw2, w2t, nullptr, HH, HH, HH);
    k_transpose<false><<<dim3(HH / 32, HH / 32, EE), 256, 0, stream>>>(ew1, ew1t, nullptr, HH, HH, HH);
    k_transpose<false><<<dim3(HM / 32, HH / 32, EE), 256, 0, stream>>>(ew2, ew2t, nullptr, HH, HM, HM);
    k_transpose<false><<<dim3(CP / 32, HM / 32, EE), 256, 0, stream>>>(ew3, ew3t, nullptr, HM, CC, CP);

    // M2 = fw2 @ kw  (3-term split MFMA, split-K=8, then reduce+transpose+split)
    k_split3<<<dim3(HH / 128, 8), 256, 0, stream>>>(fw2h, fw2l, kwth, kwtl, m2p, HH, HH / 8);
    k_m2red<<<dim3(HH / 32, 128 / 32), 256, 0, stream>>>(m2p, m2th, m2tl);
    k_bias2<<<dim3(128), 64, 0, stream>>>(fb2, kw, kb, b2);

    // features
    k_l1<<<dim3(BB / 128, HH / 128), 256, 0, stream>>>(x_hi, x_lo, w1th, w1tl, fb1, hph, hpl);
    k_l2<<<dim3(BB / 256, HH / 256), 512, 0, stream>>>(hph, w2t, fb2, featsb);

    // pk = hpre @ M2 (3-term split MFMA, split-K=4, then reduce + bias)
    k_split3<<<dim3(BB / 128, 4), 256, 0, stream>>>(hph, hpl, m2th, m2tl, pkp, HH, HH / 4);
    k_pkred<<<dim3((BB * 128) / 256), 256, 0, stream>>>(pkp, b2, pkbuf);

    // routing
    k_route<<<dim3(BB), 64, 0, stream>>>(pkbuf, keys, outW, outT, outS, top_e, top_w, cnt);
    // pkbuf is dead now; zero the slot arrays that alias it (pad slots -> b=0, w=0)
    hipMemsetAsync(W + OFF_WSL, 0, 147456, stream);
    k_offs<<<1, 1, 0, stream>>>(cnt, offs);
    k_scatter<<<dim3(BB / 256), 256, 0, stream>>>(top_e, top_w, offs, cnt2, rowsl, wslot, sl);

    // experts (top-2 only); L1 gathers feats rows in-GEMM via rowslot
    k_le<true , 4><<<dim3(NT2, HH / 256), 512, 0, stream>>>(featsb, ew1t, eb1, h1, offs, rowsl, HH, HH);
    k_le<false, 2><<<dim3(NT2, HM / 128), 512, 0, stream>>>(h1, ew2t, eb2, h2, offs, nullptr, HM, HH);
    // final: weighted per-slot partial (pf aliases h1, dead after expert L2), then combine
    k_final<<<dim3(NT2, CP / 128), 512, 0, stream>>>(h2, ew3t, eb3, pf, offs, wslot);
    k_combine<<<dim3(BB), 256, 0, stream>>>(pf, sl, outF);
}

// Round 10
// 1023.504 us; speedup vs baseline: 2.8509x; 1.2683x over previous
//
#include <hip/hip_runtime.h>

// ---------- types / helpers ----------
typedef __attribute__((ext_vector_type(8))) short short8;   // 8 x bf16 bits
typedef __attribute__((ext_vector_type(4))) float float4v;
typedef __attribute__((ext_vector_type(4))) unsigned short u16x4;

__device__ __forceinline__ float bf2f(unsigned short u) {
    union { unsigned int i; float f; } v; v.i = ((unsigned int)u) << 16; return v.f;
}
__device__ __forceinline__ unsigned short f2bf(float f) {   // round-to-nearest-even
    union { float f; unsigned int u; } v; v.f = f;
    unsigned int u = v.u;
    return (unsigned short)((u + 0x7fffu + ((u >> 16) & 1u)) >> 16);
}
__device__ __forceinline__ void load_lds16(const void* g, void* l) {
    __builtin_amdgcn_global_load_lds((const __attribute__((address_space(1))) void*)g,
                                     (__attribute__((address_space(3))) void*)l, 16, 0, 0);
}
__device__ __forceinline__ float wred(float v) {
#pragma unroll
    for (int o = 32; o > 0; o >>= 1) v += __shfl_down(v, o);
    return __shfl(v, 0);
}

// ---------- problem dims ----------
#define BB 8192
#define DD 1024
#define HH 2048
#define HM 1024
#define CC 1000
#define CP 1024
#define EE 8
#define CAP2 18432          // 72 row tiles of 256 (expert capacity, 256-padded)
#define NT2 72

// ---------- ws layout (bytes) ----------
#define OFF_XHI   0ull
#define OFF_XLO   16777216ull
#define OFF_W1TH  33554432ull
#define OFF_W1TL  37748736ull
#define OFF_W2T   41943040ull
#define OFF_HPH   50331648ull   // ends 83886080
#define OFF_HPL   83886080ull   // ends 117440512
#define OFF_M2    117440512ull  // m2th (0.5MB) + m2tl (0.5MB)
#define OFF_B2    118489088ull
#define OFF_FEATS 118490112ull  // bf16 feats, ends 152044544 (LIVE through expert L1)
#define OFF_PK    152044544ull  // ends 156238848 (kwt hi/lo early, pkbuf mid, slots late)
#define OFF_H1    0ull          // alias: x/w1t/w2t/hph region — dead after pk split3; 75.5MB
#define OFF_EW1T  156238848ull  // ends 223347712
#define OFF_H2    156238848ull  // alias ew1T (dead after expert L1); 37.7MB
#define OFF_EW2T  223347712ull
#define OFF_EW3T  256902144ull
#define OFF_TOPE  273818624ull
#define OFF_TOPW  273884160ull
#define OFF_CNT   273949696ull
// aliases
#define OFF_FW2H  OFF_HPH                  // 8.4MB, dead before l1 writes hph
#define OFF_FW2L  (OFF_HPH + 8388608ull)
#define OFF_KWTH  OFF_PK                   // 0.5MB, dead before pkred writes pkbuf
#define OFF_KWTL  (OFF_PK + 524288ull)
#define OFF_M2P   OFF_FEATS                // 8MB partials, dead before l2 writes feats
#define OFF_PKP   0ull                     // 16.8MB partials, dead before h1 written
#define OFF_WSL   OFF_PK                   // wslot[18432] f32 — pkbuf dead after k_route
#define OFF_RSL   (OFF_PK + 73728ull)      // rowslot[18432] i32
#define OFF_SL    (OFF_PK + 147456ull)     // sl[16384] i32: b -> its two slots
#define OFF_PF    0ull                     // pf[CAP2][CP] f32 (75.5MB) — aliases h1 (dead after expert L2)

// ---------- XCD-chunked grid swizzle ----------
#define SWZ_G 4
__device__ __forceinline__ void remap_xy(int& x, int& y) {
    const int nbx = gridDim.x, nby = gridDim.y;
    int lin = blockIdx.y * nbx + blockIdx.x;
    int xcd = lin & 7, idx = lin >> 3;
    int rpx = nbx >> 3;                 // row-tiles per xcd
    int gs  = rpx * SWZ_G;              // blocks per col-group within chunk
    int grp = idx / gs, wi = idx - grp * gs;
    int xl  = wi / SWZ_G, yl = wi - xl * SWZ_G;
    x = xcd * rpx + xl;
    y = grp * SWZ_G + yl;
}

// ---------- conversion kernels ----------
__global__ __launch_bounds__(256) void k_split_convert(const float* __restrict__ in,
    unsigned short* __restrict__ hi, unsigned short* __restrict__ lo, int n)
{
    int i = (blockIdx.x * 256 + threadIdx.x) * 4;
    if (i >= n) return;
    float4 v = *(const float4*)(in + i);
    unsigned short h0 = f2bf(v.x), h1 = f2bf(v.y), h2 = f2bf(v.z), h3 = f2bf(v.w);
    u16x4 hv = {h0, h1, h2, h3};
    u16x4 lv = {f2bf(v.x - bf2f(h0)), f2bf(v.y - bf2f(h1)),
                f2bf(v.z - bf2f(h2)), f2bf(v.w - bf2f(h3))};
    *(u16x4*)(hi + i) = hv;
    *(u16x4*)(lo + i) = lv;
}

// out[b][n][k] = in[b][k][n]  (bf16, zero-pad n >= N up to Npad)
template<bool SPLIT>
__global__ __launch_bounds__(256) void k_transpose(const float* __restrict__ in,
    unsigned short* __restrict__ hi, unsigned short* __restrict__ lo, int K, int N, int Npad)
{
    __shared__ float tile[32][33];
    const float* src = in + (size_t)blockIdx.z * K * N;
    int n0 = blockIdx.x * 32, k0 = blockIdx.y * 32;
    int tx = threadIdx.x & 31, ty = threadIdx.x >> 5;
#pragma unroll
    for (int r = ty; r < 32; r += 8) {
        int n = n0 + tx;
        tile[r][tx] = (n < N) ? src[(size_t)(k0 + r) * N + n] : 0.f;
    }
    __syncthreads();
    size_t ob = (size_t)blockIdx.z * Npad * K;
    {
        int n  = threadIdx.x >> 3;          // 0..31  (output row within tile)
        int kq = (threadIdx.x & 7) * 4;     // 0..28  (output col quad, contiguous in K)
        u16x4 hv, lv;
#pragma unroll
        for (int i = 0; i < 4; ++i) {
            float v = tile[kq + i][n];
            unsigned short h = f2bf(v);
            hv[i] = h;
            lv[i] = SPLIT ? f2bf(v - bf2f(h)) : (unsigned short)0;
        }
        size_t o = ob + (size_t)(n0 + n) * K + k0 + kq;
        *(u16x4*)(hi + o) = hv;
        if (SPLIT) *(u16x4*)(lo + o) = lv;
    }
}

// ============================================================================
// BK=64 4-phase core (kept for k_l2 only: grid=256 is perfectly packed at 1/CU)
// ============================================================================
template<int NB>
__device__ __forceinline__ void gemm256(
    const unsigned short* __restrict__ a0, const unsigned short* __restrict__ a1,
    const unsigned short* __restrict__ b0, const unsigned short* __restrict__ b1,
    int K, unsigned short* L, float4v (&acc)[8][NB])
{
    const int tid = threadIdx.x;
    const int lane = tid & 63, w = tid >> 6;
    const int lrow = lane & 15, quad = (lane >> 4) & 3;
    const int wm = w >> 2, wn = w & 3;
    const int NT = K >> 6;
    constexpr int BSH  = NB * 2048;         // B half-tile shorts
    constexpr int BUFS = 16384 + 2 * BSH;   // per-buffer shorts
    constexpr int VM   = (NB == 4) ? 6 : 4; // steady-state vmcnt

    int aoff[8], boff[NB];
#pragma unroll
    for (int i = 0; i < 8; ++i) {
        int r = wm * 128 + i * 16 + lrow;
        aoff[i] = r * 32 + (quad ^ ((r >> 1) & 3)) * 8;
    }
#pragma unroll
    for (int j = 0; j < NB; ++j) {
        int r = wn * (NB * 16) + j * 16 + lrow;
        boff[j] = r * 32 + (quad ^ ((r >> 1) & 3)) * 8;
    }
    unsigned short* const dA = L + w * 512;
    unsigned short* const dB = L + 16384 + w * 512;

    auto stgA = [&](int t, int kh, int buf) {
        unsigned short* d = dA + buf * BUFS + kh * 8192;
        const int ko = t * 64 + kh * 32;
        load_lds16(a0 + ko, d);
        load_lds16(a1 + ko, d + 4096);
    };
    auto stgB = [&](int t, int kh, int buf) {
        unsigned short* d = dB + buf * BUFS + kh * BSH;
        const int ko = t * 64 + kh * 32;
        load_lds16(b0 + ko, d);
        if constexpr (NB == 4) load_lds16(b1 + ko, d + 4096);
    };

    stgA(0, 0, 0); stgA(0, 1, 0); stgB(0, 0, 0); stgB(0, 1, 0);
    if (NT > 1) { stgB(1, 0, 1); stgA(1, 0, 1); stgB(1, 1, 1); }
    asm volatile("s_waitcnt vmcnt(%0)" :: "i"(VM) : "memory");
    __builtin_amdgcn_s_barrier();

    short8 af[4], bfr[NB];
    for (int t = 0; t < NT; ++t) {
        const int buf = t & 1;
        const unsigned short* Lb = L + buf * BUFS;
        // ---- P1: M-lo, k0 ----
#pragma unroll
        for (int i = 0; i < 4; ++i) af[i]  = *(const short8*)(Lb + aoff[i]);
#pragma unroll
        for (int j = 0; j < NB; ++j) bfr[j] = *(const short8*)(Lb + 16384 + boff[j]);
        if (t + 1 < NT) stgA(t + 1, 1, buf ^ 1);
        __builtin_amdgcn_s_barrier();
        __builtin_amdgcn_s_setprio(1);
#pragma unroll
        for (int i = 0; i < 4; ++i)
#pragma unroll
            for (int j = 0; j < NB; ++j)
                acc[i][j] = __builtin_amdgcn_mfma_f32_16x16x32_bf16(af[i], bfr[j], acc[i][j], 0, 0, 0);
        __builtin_amdgcn_s_setprio(0);
        __builtin_amdgcn_s_barrier();
        // ---- P2: M-hi, k0 ----
#pragma unroll
        for (int i = 0; i < 4; ++i) af[i] = *(const short8*)(Lb + aoff[4 + i]);
        if (t + 2 < NT) stgB(t + 2, 0, buf);
        __builtin_amdgcn_s_barrier();
        __builtin_amdgcn_s_setprio(1);
#pragma unroll
        for (int i = 0; i < 4; ++i)
#pragma unroll
            for (int j = 0; j < NB; ++j)
                acc[4 + i][j] = __builtin_amdgcn_mfma_f32_16x16x32_bf16(af[i], bfr[j], acc[4 + i][j], 0, 0, 0);
        __builtin_amdgcn_s_setprio(0);
        __builtin_amdgcn_s_barrier();
        // ---- P3: M-lo, k1 ----
#pragma unroll
        for (int i = 0; i < 4; ++i) af[i]  = *(const short8*)(Lb + 8192 + aoff[i]);
#pragma unroll
        for (int j = 0; j < NB; ++j) bfr[j] = *(const short8*)(Lb + 16384 + BSH + boff[j]);
        if (t + 2 < NT) stgA(t + 2, 0, buf);
        __builtin_amdgcn_s_barrier();
        __builtin_amdgcn_s_setprio(1);
#pragma unroll
        for (int i = 0; i < 4; ++i)
#pragma unroll
            for (int j = 0; j < NB; ++j)
                acc[i][j] = __builtin_amdgcn_mfma_f32_16x16x32_bf16(af[i], bfr[j], acc[i][j], 0, 0, 0);
        __builtin_amdgcn_s_setprio(0);
        __builtin_amdgcn_s_barrier();
        // ---- P4: M-hi, k1 ----
#pragma unroll
        for (int i = 0; i < 4; ++i) af[i] = *(const short8*)(Lb + 8192 + aoff[4 + i]);
        if (t + 2 < NT) {
            stgB(t + 2, 1, buf);
            asm volatile("s_waitcnt vmcnt(%0)" :: "i"(VM) : "memory");
        } else {
            asm volatile("s_waitcnt vmcnt(0)" ::: "memory");
        }
        __builtin_amdgcn_s_barrier();
        __builtin_amdgcn_s_setprio(1);
#pragma unroll
        for (int i = 0; i < 4; ++i)
#pragma unroll
            for (int j = 0; j < NB; ++j)
                acc[4 + i][j] = __builtin_amdgcn_mfma_f32_16x16x32_bf16(af[i], bfr[j], acc[4 + i][j], 0, 0, 0);
        __builtin_amdgcn_s_setprio(0);
        __builtin_amdgcn_s_barrier();
    }
}

// ============================================================================
// BK=32 TRIPLE-buffered core with counted vmcnt. 512 thr = 8 waves (2Mx4N).
// LDS: 3 buf x (A 8192 + B NB*2048 shorts) = 96KB (NB=4) / 72KB (NB=2).
// Per tile t: stage t+2 -> r2 (issue-early), P1/P2 MFMA, vmcnt(SL) (waits only
// tile t+1, in flight ~2 tiles >> HBM latency), barrier, rotate. Validated R9.
// ============================================================================
template<int NB>
__device__ __forceinline__ void gemm256b(
    const unsigned short* __restrict__ a0, const unsigned short* __restrict__ a1,
    const unsigned short* __restrict__ b0, const unsigned short* __restrict__ b1,
    int K, unsigned short* L, float4v (&acc)[8][NB])
{
    const int tid = threadIdx.x;
    const int lane = tid & 63, w = tid >> 6;
    const int lrow = lane & 15, quad = (lane >> 4) & 3;
    const int wm = w >> 2, wn = w & 3;
    const int NT = K >> 5;
    constexpr int BUFS = 8192 + NB * 2048;  // per-buffer shorts
    constexpr int SL   = (NB == 4) ? 4 : 3; // loads per stage

    int aoff[8], boff[NB];
#pragma unroll
    for (int i = 0; i < 8; ++i) {
        int r = wm * 128 + i * 16 + lrow;
        aoff[i] = r * 32 + (quad ^ ((r >> 1) & 3)) * 8;
    }
#pragma unroll
    for (int j = 0; j < NB; ++j) {
        int r = wn * (NB * 16) + j * 16 + lrow;
        boff[j] = r * 32 + (quad ^ ((r >> 1) & 3)) * 8;
    }
    const int dAo = w * 512;            // wave-uniform LDS dest offsets
    const int dBo = 8192 + w * 512;

    auto stg = [&](int t, unsigned short* buf) {   // stage full K-tile t into buf
        const int ko = t * 32;
        load_lds16(a0 + ko, buf + dAo);            // M-lo rows
        load_lds16(a1 + ko, buf + dAo + 4096);     // M-hi rows
        load_lds16(b0 + ko, buf + dBo);
        if constexpr (NB == 4) load_lds16(b1 + ko, buf + dBo + 4096);
    };

    unsigned short* r0 = L;              // tile t   (read)
    unsigned short* r1 = L + BUFS;       // tile t+1 (in flight)
    unsigned short* r2 = L + 2 * BUFS;   // tile t+2 (stage target)

    stg(0, r0);
    if (NT > 1) {
        stg(1, r1);
        asm volatile("s_waitcnt vmcnt(%0)" :: "i"(SL) : "memory");
    } else {
        asm volatile("s_waitcnt vmcnt(0)" ::: "memory");
    }
    __builtin_amdgcn_sched_barrier(0);
    __builtin_amdgcn_s_barrier();
    __builtin_amdgcn_sched_barrier(0);

    short8 af[4], bfr[NB];
    for (int t = 0; t < NT; ++t) {
        if (t + 2 < NT) stg(t + 2, r2);     // issue-early: 2-tile flight window
        // ---- P1: M-lo ----
#pragma unroll
        for (int i = 0; i < 4; ++i) af[i]  = *(const short8*)(r0 + aoff[i]);
#pragma unroll
        for (int j = 0; j < NB; ++j) bfr[j] = *(const short8*)(r0 + 8192 + boff[j]);
        __builtin_amdgcn_s_setprio(1);
#pragma unroll
        for (int i = 0; i < 4; ++i)
#pragma unroll
            for (int j = 0; j < NB; ++j)
                acc[i][j] = __builtin_amdgcn_mfma_f32_16x16x32_bf16(af[i], bfr[j], acc[i][j], 0, 0, 0);
        __builtin_amdgcn_s_setprio(0);
        // ---- P2: M-hi (reuse bfr) ----
#pragma unroll
        for (int i = 0; i < 4; ++i) af[i] = *(const short8*)(r0 + aoff[4 + i]);
        __builtin_amdgcn_s_setprio(1);
#pragma unroll
        for (int i = 0; i < 4; ++i)
#pragma unroll
            for (int j = 0; j < NB; ++j)
                acc[4 + i][j] = __builtin_amdgcn_mfma_f32_16x16x32_bf16(af[i], bfr[j], acc[4 + i][j], 0, 0, 0);
        __builtin_amdgcn_s_setprio(0);
        if (t + 2 < NT)
            asm volatile("s_waitcnt vmcnt(%0)" :: "i"(SL) : "memory");
        else
            asm volatile("s_waitcnt vmcnt(0)" ::: "memory");
        __builtin_amdgcn_sched_barrier(0);
        __builtin_amdgcn_s_barrier();
        __builtin_amdgcn_sched_barrier(0);
        unsigned short* tmp = r0; r0 = r1; r1 = r2; r2 = tmp;   // rotate
    }
}

// ---------- layer 1: split (bf16x2) GEMM, relu, split-store (128^2 structure) ----------
__global__ __launch_bounds__(256, 2) void k_l1(
    const unsigned short* __restrict__ xh, const unsigned short* __restrict__ xl,
    const unsigned short* __restrict__ wh, const unsigned short* __restrict__ wl,
    const float* __restrict__ bias, unsigned short* __restrict__ oh, unsigned short* __restrict__ ol)
{
    __shared__ __align__(16) unsigned short Ash[4096], Asl[4096], Bsh[4096], Bsl[4096];
    const int K = DD, N = HH;
    int bx, by; remap_xy(bx, by);
    const int row0 = bx * 128, col0 = by * 128;
    const int t = threadIdx.x, lane = t & 63, w = t >> 6;
    const int lrow = lane & 15, quad = lane >> 4;
    const int swz = (quad ^ ((lrow >> 1) & 3)) * 8;
    const int wr = (w & 1) * 64, wc = (w >> 1) * 64;
    float4v acc[4][4] = {};
    for (int k0 = 0; k0 < K; k0 += 32) {
#pragma unroll
        for (int p = 0; p < 2; ++p) {
            int c = p * 256 + t;
            int r = c >> 2, q = (c & 3) ^ ((r >> 1) & 3);
            size_t ga = (size_t)(row0 + r) * K + k0 + q * 8;
            size_t gb = (size_t)(col0 + r) * K + k0 + q * 8;
            int lo_ = (p * 256 + w * 64) * 8;
            load_lds16(xh + ga, Ash + lo_);
            load_lds16(xl + ga, Asl + lo_);
            load_lds16(wh + gb, Bsh + lo_);
            load_lds16(wl + gb, Bsl + lo_);
        }
        __syncthreads();
        short8 ah[4], al[4], bh[4], bl[4];
#pragma unroll
        for (int i = 0; i < 4; ++i) {
            int o = (wr + i * 16 + lrow) * 32 + swz;
            ah[i] = *(const short8*)(Ash + o);
            al[i] = *(const short8*)(Asl + o);
        }
#pragma unroll
        for (int j = 0; j < 4; ++j) {
            int o = (wc + j * 16 + lrow) * 32 + swz;
            bh[j] = *(const short8*)(Bsh + o);
            bl[j] = *(const short8*)(Bsl + o);
        }
#pragma unroll
        for (int i = 0; i < 4; ++i)
#pragma unroll
            for (int j = 0; j < 4; ++j) {
                float4v a0 = __builtin_amdgcn_mfma_f32_16x16x32_bf16(al[i], bh[j], acc[i][j], 0, 0, 0);
                a0 = __builtin_amdgcn_mfma_f32_16x16x32_bf16(ah[i], bl[j], a0, 0, 0, 0);
                acc[i][j] = __builtin_amdgcn_mfma_f32_16x16x32_bf16(ah[i], bh[j], a0, 0, 0, 0);
            }
        __syncthreads();
    }
#pragma unroll
    for (int i = 0; i < 4; ++i)
#pragma unroll
        for (int r = 0; r < 4; ++r) {
            int row = row0 + wr + i * 16 + quad * 4 + r;
            size_t base = (size_t)row * N;
#pragma unroll
            for (int j = 0; j < 4; ++j) {
                int col = col0 + wc + j * 16 + lrow;
                float v = fmaxf(acc[i][j][r] + bias[col], 0.f);
                unsigned short h = f2bf(v);
                oh[base + col] = h;
                ol[base + col] = f2bf(v - bf2f(h));
            }
        }
}

// ---------- generic 3-term split GEMM, N=128, split-K, fp32 partial out ----------
__global__ __launch_bounds__(256, 2) void k_split3(
    const unsigned short* __restrict__ ah_, const unsigned short* __restrict__ al_,
    const unsigned short* __restrict__ bh_, const unsigned short* __restrict__ bl_,
    float* __restrict__ out, int K, int klen)
{
    __shared__ __align__(16) unsigned short Ash[4096], Asl[4096], Bsh[4096], Bsl[4096];
    const int row0 = blockIdx.x * 128;
    const int kb = blockIdx.y * klen;
    out += (size_t)blockIdx.y * gridDim.x * 128 * 128;
    const int t = threadIdx.x, lane = t & 63, w = t >> 6;
    const int lrow = lane & 15, quad = lane >> 4;
    const int swz = (quad ^ ((lrow >> 1) & 3)) * 8;
    const int wr = (w & 1) * 64, wc = (w >> 1) * 64;
    float4v acc[4][4] = {};
    for (int k0 = kb; k0 < kb + klen; k0 += 32) {
#pragma unroll
        for (int p = 0; p < 2; ++p) {
            int c = p * 256 + t;
            int r = c >> 2, q = (c & 3) ^ ((r >> 1) & 3);
            size_t ga = (size_t)(row0 + r) * K + k0 + q * 8;
            size_t gb = (size_t)r * K + k0 + q * 8;           // B has exactly 128 rows
            int lo_ = (p * 256 + w * 64) * 8;
            load_lds16(ah_ + ga, Ash + lo_);
            load_lds16(al_ + ga, Asl + lo_);
            load_lds16(bh_ + gb, Bsh + lo_);
            load_lds16(bl_ + gb, Bsl + lo_);
        }
        __syncthreads();
        short8 ah[4], al[4], bh[4], bl[4];
#pragma unroll
        for (int i = 0; i < 4; ++i) {
            int o = (wr + i * 16 + lrow) * 32 + swz;
            ah[i] = *(const short8*)(Ash + o);
            al[i] = *(const short8*)(Asl + o);
        }
#pragma unroll
        for (int j = 0; j < 4; ++j) {
            int o = (wc + j * 16 + lrow) * 32 + swz;
            bh[j] = *(const short8*)(Bsh + o);
            bl[j] = *(const short8*)(Bsl + o);
        }
#pragma unroll
        for (int i = 0; i < 4; ++i)
#pragma unroll
            for (int j = 0; j < 4; ++j) {
                float4v a0 = __builtin_amdgcn_mfma_f32_16x16x32_bf16(al[i], bh[j], acc[i][j], 0, 0, 0);
                a0 = __builtin_amdgcn_mfma_f32_16x16x32_bf16(ah[i], bl[j], a0, 0, 0, 0);
                acc[i][j] = __builtin_amdgcn_mfma_f32_16x16x32_bf16(ah[i], bh[j], a0, 0, 0, 0);
            }
        __syncthreads();
    }
#pragma unroll
    for (int i = 0; i < 4; ++i)
#pragma unroll
        for (int r = 0; r < 4; ++r) {
            int row = row0 + wr + i * 16 + quad * 4 + r;
            size_t base = (size_t)row * 128;
#pragma unroll
            for (int j = 0; j < 4; ++j) {
                int col = wc + j * 16 + lrow;
                out[base + col] = acc[i][j][r];
            }
        }
}

// ---------- M2 reduce: sum 8 partials, transpose, split to bf16 hi/lo ----------
__global__ __launch_bounds__(256) void k_m2red(const float* __restrict__ p,
    unsigned short* __restrict__ th, unsigned short* __restrict__ tl)
{
    __shared__ float tile[32][33];
    const int h0 = blockIdx.x * 32, c0 = blockIdx.y * 32;
    const int t = threadIdx.x;
    {
        int r = t >> 3, cq = (t & 7) * 4;
        size_t base = (size_t)(h0 + r) * 128 + c0 + cq;
        float4 s = *(const float4*)(p + base);
#pragma unroll
        for (int ks = 1; ks < 8; ++ks) {
            float4 v = *(const float4*)(p + (size_t)ks * HH * 128 + base);
            s.x += v.x; s.y += v.y; s.z += v.z; s.w += v.w;
        }
        tile[r][cq] = s.x; tile[r][cq + 1] = s.y; tile[r][cq + 2] = s.z; tile[r][cq + 3] = s.w;
    }
    __syncthreads();
    {
        int cr = t >> 3, hq = (t & 7) * 4;
        u16x4 hv, lv;
#pragma unroll
        for (int i = 0; i < 4; ++i) {
            float v = tile[hq + i][cr];
            unsigned short h = f2bf(v);
            hv[i] = h; lv[i] = f2bf(v - bf2f(h));
        }
        size_t o = (size_t)(c0 + cr) * HH + h0 + hq;
        *(u16x4*)(th + o) = hv;
        *(u16x4*)(tl + o) = lv;
    }
}

// ---------- pk reduce: sum 4 partials + bias ----------
__global__ __launch_bounds__(256) void k_pkred(const float* __restrict__ p,
    const float* __restrict__ b2, float* __restrict__ out)
{
    int idx = blockIdx.x * 256 + threadIdx.x;
    const size_t S = (size_t)BB * 128;
    out[idx] = p[idx] + p[idx + S] + p[idx + 2 * S] + p[idx + 3 * S] + b2[idx & 127];
}

// ---------- layer 2: single bf16 GEMM -> feats bf16 (no relu), 256^2 BK=64 ----------
__global__ __launch_bounds__(512, 2) void k_l2(const unsigned short* __restrict__ A,
    const unsigned short* __restrict__ Bt, const float* __restrict__ bias,
    unsigned short* __restrict__ outb)
{
    __shared__ __align__(16) unsigned short L[65536];
    const int K = HH, N = HH;
    int bx, by; remap_xy(bx, by);
    const int row0 = bx * 256, col0 = by * 256;
    const int tid = threadIdx.x;
    const int r0 = tid >> 2, c0 = tid & 3;
    const int csw = (c0 ^ ((r0 >> 1) & 3)) * 8;
    const unsigned short* a0 = A + (size_t)(row0 + r0) * K + csw;
    const unsigned short* a1 = a0 + (size_t)128 * K;
    const unsigned short* b0 = Bt + (size_t)(col0 + r0) * K + csw;
    const unsigned short* b1 = b0 + (size_t)128 * K;
    float4v acc[8][4] = {};
    gemm256<4>(a0, a1, b0, b1, K, L, acc);
    const int lane = tid & 63, w = tid >> 6;
    const int lrow = lane & 15, quad = (lane >> 4) & 3;
    const int wm = w >> 2, wn = w & 3;
#pragma unroll
    for (int ii = 0; ii < 8; ++ii)
#pragma unroll
        for (int rr = 0; rr < 4; ++rr) {
            int row = row0 + wm * 128 + ii * 16 + quad * 4 + rr;
            size_t base = (size_t)row * N;
#pragma unroll
            for (int j = 0; j < 4; ++j) {
                int col = col0 + wn * 64 + j * 16 + lrow;
                outb[base + col] = f2bf(acc[ii][j][rr] + bias[col]);
            }
        }
}

// ---------- expert GEMM (relu, bf16 out), 256xBN BK=32 3-buf; IND: rows via rowslot ----------
template<bool IND, int NB>
__global__ __launch_bounds__(512, 2) void k_le(const unsigned short* __restrict__ A,
    const unsigned short* __restrict__ WT, const float* __restrict__ bias,
    unsigned short* __restrict__ out, const int* __restrict__ offs,
    const int* __restrict__ rowslot, int N, int K)
{
    __shared__ __align__(16) unsigned short L[3 * (8192 + NB * 2048)];
    int bx, by; remap_xy(bx, by);
    const int row0 = bx * 256;
    if (row0 >= offs[8]) return;
    int e = 0;
#pragma unroll
    for (int i = 1; i < 8; ++i) if (offs[i] <= row0) e = i;
    const unsigned short* Bt = WT + (size_t)e * N * K;
    const float* bs = bias + (size_t)e * N;
    const int col0 = by * (NB * 64);
    const int tid = threadIdx.x;
    const int r0 = tid >> 2, c0 = tid & 3;
    const int csw = (c0 ^ ((r0 >> 1) & 3)) * 8;
    const int gr0 = IND ? rowslot[row0 + r0] : (row0 + r0);
    const int gr1 = IND ? rowslot[row0 + 128 + r0] : (row0 + 128 + r0);
    const unsigned short* a0 = A + (size_t)gr0 * K + csw;
    const unsigned short* a1 = A + (size_t)gr1 * K + csw;
    const unsigned short* b0 = Bt + (size_t)(col0 + r0) * K + csw;
    const unsigned short* b1 = b0 + (size_t)128 * K;
    float4v acc[8][NB] = {};
    gemm256b<NB>(a0, a1, b0, b1, K, L, acc);
    const int lane = tid & 63, w = tid >> 6;
    const int lrow = lane & 15, quad = (lane >> 4) & 3;
    const int wm = w >> 2, wn = w & 3;
#pragma unroll
    for (int ii = 0; ii < 8; ++ii)
#pragma unroll
        for (int rr = 0; rr < 4; ++rr) {
            int row = row0 + wm * 128 + ii * 16 + quad * 4 + rr;
            size_t base = (size_t)row * N;
#pragma unroll
            for (int j = 0; j < NB; ++j) {
                int col = col0 + wn * (NB * 16) + j * 16 + lrow;
                out[base + col] = f2bf(fmaxf(acc[ii][j][rr] + bs[col], 0.f));
            }
        }
}

// ---------- final expert GEMM: weighted per-slot partial (NO atomics), BK=32 3-buf ----------
__global__ __launch_bounds__(512, 2) void k_final(const unsigned short* __restrict__ A,
    const unsigned short* __restrict__ WT, const float* __restrict__ bias,
    float* __restrict__ pf, const int* __restrict__ offs,
    const float* __restrict__ wslot)
{
    constexpr int NB = 2;
    __shared__ __align__(16) unsigned short L[3 * (8192 + NB * 2048)];
    const int N = CP, K = HM;
    int bx, by; remap_xy(bx, by);
    const int row0 = bx * 256;
    if (row0 >= offs[8]) return;
    int e = 0;
#pragma unroll
    for (int i = 1; i < 8; ++i) if (offs[i] <= row0) e = i;
    const unsigned short* Bt = WT + (size_t)e * N * K;
    const float* bs = bias + (size_t)e * CC;
    const int col0 = by * (NB * 64);
    const int tid = threadIdx.x;
    const int r0 = tid >> 2, c0 = tid & 3;
    const int csw = (c0 ^ ((r0 >> 1) & 3)) * 8;
    const unsigned short* a0 = A + (size_t)(row0 + r0) * K + csw;
    const unsigned short* a1 = a0 + (size_t)128 * K;
    const unsigned short* b0 = Bt + (size_t)(col0 + r0) * K + csw;
    float4v acc[8][NB] = {};
    gemm256b<NB>(a0, a1, b0, b0, K, L, acc);
    const int lane = tid & 63, w = tid >> 6;
    const int lrow = lane & 15, quad = (lane >> 4) & 3;
    const int wm = w >> 2, wn = w & 3;
#pragma unroll
    for (int ii = 0; ii < 8; ++ii)
#pragma unroll
        for (int rr = 0; rr < 4; ++rr) {
            int row = row0 + wm * 128 + ii * 16 + quad * 4 + rr;
            float wv = wslot[row];
            if (wv != 0.f) {
                float* prow = pf + (size_t)row * CP;
#pragma unroll
                for (int j = 0; j < NB; ++j) {
                    int col = col0 + wn * (NB * 16) + j * 16 + lrow;
                    if (col < CC) prow[col] = wv * (acc[ii][j][rr] + bs[col]);
                }
            }
        }
}

// ---------- combine: outF[b][c] = pf[sl[2b]][c] + pf[sl[2b+1]][c] ----------
__global__ __launch_bounds__(256) void k_combine(const float* __restrict__ pf,
    const int* __restrict__ sl, float* __restrict__ outF)
{
    int b = blockIdx.x;
    int c = threadIdx.x * 4;
    if (c >= CC) return;
    int s0 = sl[b * 2], s1 = sl[b * 2 + 1];
    float4 v0 = *(const float4*)(pf + (size_t)s0 * CP + c);
    float4 v1 = *(const float4*)(pf + (size_t)s1 * CP + c);
    float4 r; r.x = v0.x + v1.x; r.y = v0.y + v1.y; r.z = v0.z + v1.z; r.w = v0.w + v1.w;
    *(float4*)(outF + (size_t)b * CC + c) = r;
}

// ---------- b2[c] = sum_j fb2[j]*kw[j,c] + kb[c] ----------
__global__ __launch_bounds__(64) void k_bias2(const float* __restrict__ fb2,
    const float* __restrict__ kw, const float* __restrict__ kb, float* __restrict__ b2)
{
    int c = blockIdx.x, lane = threadIdx.x;
    float s = 0.f;
    for (int j = lane; j < HH; j += 64) s += fb2[j] * kw[(size_t)j * 128 + c];
    s = wred(s);
    if (lane == 0) b2[c] = s + kb[c];
}

// ---------- routing (R10): 32 rows/block, 16-lane groups, LDS keys + histogram ----------
// Old version: 8192 1-wave blocks, 9x 6-step 64-lane wred chains per row, key
// norms recomputed 8192x, and 16384 contended global atomics on 8 counters
// (~192us). New: 256 blocks x 256 thr; keys+inv-norms in LDS once per block;
// each 16-lane group reduces one row via 4-step shfl_xor butterfly; counts via
// LDS histogram -> 8 global atomics per block (2048 total, 8x fewer).
__global__ __launch_bounds__(256) void k_route(const float* __restrict__ pk,
    const float* __restrict__ keys, float* __restrict__ wout, float* __restrict__ tout,
    float* __restrict__ simout, int* __restrict__ top_e, float* __restrict__ top_w,
    int* __restrict__ cnt)
{
    __shared__ float kl[8][128];
    __shared__ float kinv[8];
    __shared__ int hcnt[8];
    const int t = threadIdx.x;
    {   // stage keys (8x128 f32 = 4KB): 256 threads x 4 floats
        float4 v = *(const float4*)(keys + t * 4);
        *(float4*)(&kl[0][0] + t * 4) = v;
    }
    if (t < 8) hcnt[t] = 0;
    __syncthreads();
    if (t < 8) {   // per-expert inverse norm, once per block
        float s = 0.f;
#pragma unroll 16
        for (int j = 0; j < 128; ++j) s += kl[t][j] * kl[t][j];
        kinv[t] = 1.f / fmaxf(sqrtf(s), 1e-12f);
    }
    __syncthreads();

    const int w = t >> 6, lane = t & 63;
    const int g = lane >> 4, gl = lane & 15;    // 4 row-groups of 16 lanes
    const int b0 = blockIdx.x * 32;
#pragma unroll
    for (int it = 0; it < 2; ++it) {
        const int b = b0 + w * 8 + it * 4 + g;
        const float* pr = pk + (size_t)b * 128 + gl * 8;
        float4 v0 = *(const float4*)pr;
        float4 v1 = *(const float4*)(pr + 4);
        float nrm = v0.x * v0.x + v0.y * v0.y + v0.z * v0.z + v0.w * v0.w
                  + v1.x * v1.x + v1.y * v1.y + v1.z * v1.z + v1.w * v1.w;
        float d[8];
#pragma unroll
        for (int e = 0; e < 8; ++e) {
            const float* kr = &kl[e][gl * 8];
            d[e] = v0.x * kr[0] + v0.y * kr[1] + v0.z * kr[2] + v0.w * kr[3]
                 + v1.x * kr[4] + v1.y * kr[5] + v1.z * kr[6] + v1.w * kr[7];
        }
#pragma unroll
        for (int o = 1; o < 16; o <<= 1) {      // butterfly within 16-lane group
            nrm += __shfl_xor(nrm, o);
#pragma unroll
            for (int e = 0; e < 8; ++e) d[e] += __shfl_xor(d[e], o);
        }
        if (gl == 0) {
            float inv = 1.f / fmaxf(sqrtf(nrm), 1e-12f);
            float sims[8];
#pragma unroll
            for (int e = 0; e < 8; ++e) sims[e] = d[e] * inv * kinv[e];
            int i1 = 0; float v1s = sims[0];
#pragma unroll
            for (int e = 1; e < 8; ++e) if (sims[e] > v1s) { v1s = sims[e]; i1 = e; }
            int i2 = -1; float v2s = -1e30f;
#pragma unroll
            for (int e = 0; e < 8; ++e) if (e != i1 && sims[e] > v2s) { v2s = sims[e]; i2 = e; }
            float e2 = expf(v2s - v1s);
            float w1 = 1.f / (1.f + e2), w2 = e2 / (1.f + e2);
#pragma unroll
            for (int e = 0; e < 8; ++e) simout[(size_t)b * 8 + e] = sims[e];
            wout[(size_t)b * 8 + i1] = w1;
            wout[(size_t)b * 8 + i2] = w2;
            tout[(size_t)b * 2] = (float)i1; tout[(size_t)b * 2 + 1] = (float)i2;
            top_e[b * 2] = i1; top_e[b * 2 + 1] = i2;
            top_w[b * 2] = w1; top_w[b * 2 + 1] = w2;
            atomicAdd(&hcnt[i1], 1); atomicAdd(&hcnt[i2], 1);   // LDS, fast
        }
    }
    __syncthreads();
    if (t < 8 && hcnt[t] > 0) atomicAdd(&cnt[t], hcnt[t]);      // 8 global atomics/block
}

__global__ void k_offs(const int* __restrict__ cnt, int* __restrict__ offs)
{
    if (threadIdx.x == 0) {
        int o = 0;
        for (int e = 0; e < 8; ++e) { offs[e] = o; o += ((cnt[e] + 255) >> 8) << 8; }
        offs[8] = o;
    }
}

// ---------- scatter (R10): per-block LDS ticket, 8 global atomics per block ----------
__global__ __launch_bounds__(256) void k_scatter(const int* __restrict__ top_e,
    const float* __restrict__ top_w, const int* __restrict__ offs, int* __restrict__ cnt2,
    int* __restrict__ rowslot, float* __restrict__ wslot, int* __restrict__ sl)
{
    __shared__ int lcnt[8], lbase[8];
    const int t = threadIdx.x;
    if (t < 8) lcnt[t] = 0;
    __syncthreads();
    const int b = blockIdx.x * 256 + t;
    const int e0 = top_e[b * 2], e1 = top_e[b * 2 + 1];
    const float w0 = top_w[b * 2], w1 = top_w[b * 2 + 1];
    const int r0 = atomicAdd(&lcnt[e0], 1);     // LDS ticket
    const int r1 = atomicAdd(&lcnt[e1], 1);
    __syncthreads();
    if (t < 8) lbase[t] = (lcnt[t] > 0) ? atomicAdd(&cnt2[t], lcnt[t]) : 0;
    __syncthreads();
    int s0 = offs[e0] + lbase[e0] + r0;
    int s1 = offs[e1] + lbase[e1] + r1;
    rowslot[s0] = b; wslot[s0] = w0; sl[b * 2] = s0;
    rowslot[s1] = b; wslot[s1] = w1; sl[b * 2 + 1] = s1;
}

// ---------- launch ----------
extern "C" void kernel_launch(void* const* d_in, const int* in_sizes, int n_in,
                              void* d_out, int out_size, void* d_ws, size_t ws_size,
                              hipStream_t stream)
{
    const float* x    = (const float*)d_in[0];
    const float* fw1  = (const float*)d_in[1];
    const float* fb1  = (const float*)d_in[2];
    const float* fw2  = (const float*)d_in[3];
    const float* fb2  = (const float*)d_in[4];
    const float* kw   = (const float*)d_in[5];
    const float* kb   = (const float*)d_in[6];
    const float* keys = (const float*)d_in[7];
    const float* ew1  = (const float*)d_in[8];
    const float* eb1  = (const float*)d_in[9];
    const float* ew2  = (const float*)d_in[10];
    const float* eb2  = (const float*)d_in[11];
    const float* ew3  = (const float*)d_in[12];
    const float* eb3  = (const float*)d_in[13];

    char* W = (char*)d_ws;
    unsigned short* x_hi  = (unsigned short*)(W + OFF_XHI);
    unsigned short* x_lo  = (unsigned short*)(W + OFF_XLO);
    unsigned short* w1th  = (unsigned short*)(W + OFF_W1TH);
    unsigned short* w1tl  = (unsigned short*)(W + OFF_W1TL);
    unsigned short* w2t   = (unsigned short*)(W + OFF_W2T);
    unsigned short* hph   = (unsigned short*)(W + OFF_HPH);
    unsigned short* hpl   = (unsigned short*)(W + OFF_HPL);
    unsigned short* fw2h  = (unsigned short*)(W + OFF_FW2H);
    unsigned short* fw2l  = (unsigned short*)(W + OFF_FW2L);
    unsigned short* kwth  = (unsigned short*)(W + OFF_KWTH);
    unsigned short* kwtl  = (unsigned short*)(W + OFF_KWTL);
    unsigned short* m2th  = (unsigned short*)(W + OFF_M2);
    unsigned short* m2tl  = (unsigned short*)(W + OFF_M2 + 524288ull);
    float*          m2p   = (float*)(W + OFF_M2P);
    float*          pkp   = (float*)(W + OFF_PKP);
    float*          b2    = (float*)(W + OFF_B2);
    unsigned short* featsb= (unsigned short*)(W + OFF_FEATS);
    float*          pkbuf = (float*)(W + OFF_PK);
    unsigned short* h1    = (unsigned short*)(W + OFF_H1);
    unsigned short* h2    = (unsigned short*)(W + OFF_H2);
    float*          pf    = (float*)(W + OFF_PF);
    unsigned short* ew1t  = (unsigned short*)(W + OFF_EW1T);
    unsigned short* ew2t  = (unsigned short*)(W + OFF_EW2T);
    unsigned short* ew3t  = (unsigned short*)(W + OFF_EW3T);
    float*          wslot = (float*)(W + OFF_WSL);
    int*            rowsl = (int*)(W + OFF_RSL);
    int*            sl    = (int*)(W + OFF_SL);
    int*            top_e = (int*)(W + OFF_TOPE);
    float*          top_w = (float*)(W + OFF_TOPW);
    int*            cnt   = (int*)(W + OFF_CNT);
    int*            cnt2  = cnt + 8;
    int*            offs  = cnt + 16;

    float* outF = (float*)d_out;
    float* outW = outF + 8192000;
    float* outT = outF + 8257536;
    float* outS = outF + 8273920;

    // outF/outT/outS are fully written by k_combine/k_route; only outW is scattered.
    hipMemsetAsync(outW, 0, 65536 * sizeof(float), stream);
    hipMemsetAsync(W + OFF_CNT, 0, 256, stream);

    // conversions / transposes (ws is re-poisoned every call; must redo each launch)
    k_split_convert<<<dim3((BB * DD) / 1024), 256, 0, stream>>>(x, x_hi, x_lo, BB * DD);
    k_split_convert<<<dim3((HH * HH) / 1024), 256, 0, stream>>>(fw2, fw2h, fw2l, HH * HH);
    k_transpose<true ><<<dim3(128 / 32, HH / 32, 1), 256, 0, stream>>>(kw, kwth, kwtl, HH, 128, 128);
    k_transpose<true ><<<dim3(HH / 32, DD / 32, 1), 256, 0, stream>>>(fw1, w1th, w1tl, DD, HH, HH);
    k_transpose<false><<<dim3(HH / 32, HH / 32, 1), 256, 0, stream>>>(fw2, w2t, nullptr, HH, HH, HH);
    k_transpose<false><<<dim3(HH / 32, HH / 32, EE), 256, 0, stream>>>(ew1, ew1t, nullptr, HH, HH, HH);
    k_transpose<false><<<dim3(HM / 32, HH / 32, EE), 256, 0, stream>>>(ew2, ew2t, nullptr, HH, HM, HM);
    k_transpose<false><<<dim3(CP / 32, HM / 32, EE), 256, 0, stream>>>(ew3, ew3t, nullptr, HM, CC, CP);

    // M2 = fw2 @ kw  (3-term split MFMA, split-K=8, then reduce+transpose+split)
    k_split3<<<dim3(HH / 128, 8), 256, 0, stream>>>(fw2h, fw2l, kwth, kwtl, m2p, HH, HH / 8);
    k_m2red<<<dim3(HH / 32, 128 / 32), 256, 0, stream>>>(m2p, m2th, m2tl);
    k_bias2<<<dim3(128), 64, 0, stream>>>(fb2, kw, kb, b2);

    // features
    k_l1<<<dim3(BB / 128, HH / 128), 256, 0, stream>>>(x_hi, x_lo, w1th, w1tl, fb1, hph, hpl);
    k_l2<<<dim3(BB / 256, HH / 256), 512, 0, stream>>>(hph, w2t, fb2, featsb);

    // pk = hpre @ M2 (3-term split MFMA, split-K=4, then reduce + bias)
    k_split3<<<dim3(BB / 128, 4), 256, 0, stream>>>(hph, hpl, m2th, m2tl, pkp, HH, HH / 4);
    k_pkred<<<dim3((BB * 128) / 256), 256, 0, stream>>>(pkp, b2, pkbuf);

    // routing
    k_route<<<dim3(BB / 32), 256, 0, stream>>>(pkbuf, keys, outW, outT, outS, top_e, top_w, cnt);
    // pkbuf is dead now; zero the slot arrays that alias it (pad slots -> b=0, w=0)
    hipMemsetAsync(W + OFF_WSL, 0, 147456, stream);
    k_offs<<<1, 1, 0, stream>>>(cnt, offs);
    k_scatter<<<dim3(BB / 256), 256, 0, stream>>>(top_e, top_w, offs, cnt2, rowsl, wslot, sl);

    // experts (top-2 only); L1 gathers feats rows in-GEMM via rowslot
    k_le<true , 4><<<dim3(NT2, HH / 256), 512, 0, stream>>>(featsb, ew1t, eb1, h1, offs, rowsl, HH, HH);
    k_le<false, 2><<<dim3(NT2, HM / 128), 512, 0, stream>>>(h1, ew2t, eb2, h2, offs, nullptr, HM, HH);
    // final: weighted per-slot partial (pf aliases h1, dead after expert L2), then combine
    k_final<<<dim3(NT2, CP / 128), 512, 0, stream>>>(h2, ew3t, eb3, pf, offs, wslot);
    k_combine<<<dim3(BB), 256, 0, stream>>>(pf, sl, outF);
}